// Round 1
// baseline (1304.775 us; speedup 1.0000x reference)
//
#include <hip/hip_runtime.h>
#include <hip/hip_bf16.h>
#include <math.h>

#define N_NODES 100000
#define N_EDGES 600000
#define F_IN 128
#define F_HID 256
#define F_OUT 24

// ---------------- zero workspace (agg1 + aggz contiguous) ----------------
__global__ __launch_bounds__(256) void zero_f4(float4* __restrict__ p, int n4) {
  int i = blockIdx.x * 256 + threadIdx.x;
  int stride = gridDim.x * 256;
  float4 z = make_float4(0.f, 0.f, 0.f, 0.f);
  for (; i < n4; i += stride) p[i] = z;
}

// ---------------- scatter1: agg1[dst] += x[src]  (128 floats/edge) -------
__global__ __launch_bounds__(256) void scatter128(
    const float* __restrict__ x, const int* __restrict__ src,
    const int* __restrict__ dst, float* __restrict__ agg) {
  int tid = blockIdx.x * 256 + threadIdx.x;
  int e = tid >> 5;                 // 32 threads per edge, float4 each
  if (e >= N_EDGES) return;
  int c = (tid & 31) << 2;
  int s = src[e], d = dst[e];
  float4 v = *reinterpret_cast<const float4*>(x + (size_t)s * F_IN + c);
  float* p = agg + (size_t)d * F_IN + c;
  atomicAdd(p + 0, v.x);
  atomicAdd(p + 1, v.y);
  atomicAdd(p + 2, v.z);
  atomicAdd(p + 3, v.w);
}

__device__ inline unsigned short f2bf(float f) {
  __hip_bfloat16 h = __float2bfloat16(f);
  return *reinterpret_cast<unsigned short*>(&h);
}

// ---------------- GEMM1: h1 = relu((x+agg1) @ W1 + b1), bf16 out --------
// M=100000, K=128, N=256. 64x64 tile, BK=32, 256 threads, 4x4 per thread.
__global__ __launch_bounds__(256) void gemm1(
    const float* __restrict__ x, const float* __restrict__ agg,
    const float* __restrict__ W1, const float* __restrict__ b1,
    __hip_bfloat16* __restrict__ h1) {
  __shared__ float As[32][64];  // [k][row]  (transposed for float4 reads)
  __shared__ float Bs[32][64];  // [k][col]
  int t = threadIdx.x;
  int tx = t & 15, ty = t >> 4;
  int row0 = blockIdx.y * 64, col0 = blockIdx.x * 64;
  float acc[4][4] = {{0.f}};

  for (int ko = 0; ko < F_IN; ko += 32) {
#pragma unroll
    for (int rep = 0; rep < 2; ++rep) {
      int i = t * 4 + rep * 1024;
      // A tile: 64 rows x 32 k
      int r = i >> 5, ck = i & 31;
      int grow = row0 + r;
      float4 v = make_float4(0.f, 0.f, 0.f, 0.f);
      if (grow < N_NODES) {
        float4 a = *(const float4*)(x + (size_t)grow * F_IN + ko + ck);
        float4 g = *(const float4*)(agg + (size_t)grow * F_IN + ko + ck);
        v = make_float4(a.x + g.x, a.y + g.y, a.z + g.z, a.w + g.w);
      }
      As[ck + 0][r] = v.x;
      As[ck + 1][r] = v.y;
      As[ck + 2][r] = v.z;
      As[ck + 3][r] = v.w;
      // B tile: 32 k x 64 cols
      int k = i >> 6, c2 = i & 63;
      *(float4*)&Bs[k][c2] =
          *(const float4*)(W1 + (size_t)(ko + k) * F_HID + col0 + c2);
    }
    __syncthreads();
#pragma unroll
    for (int k = 0; k < 32; ++k) {
      float4 a4 = *(const float4*)&As[k][ty * 4];
      float4 b4 = *(const float4*)&Bs[k][tx * 4];
      float a[4] = {a4.x, a4.y, a4.z, a4.w};
      float b[4] = {b4.x, b4.y, b4.z, b4.w};
#pragma unroll
      for (int ii = 0; ii < 4; ++ii)
#pragma unroll
        for (int jj = 0; jj < 4; ++jj) acc[ii][jj] += a[ii] * b[jj];
    }
    __syncthreads();
  }

#pragma unroll
  for (int ii = 0; ii < 4; ++ii) {
    int grow = row0 + ty * 4 + ii;
    if (grow >= N_NODES) break;
    int gcol = col0 + tx * 4;
    float v0 = fmaxf(acc[ii][0] + b1[gcol + 0], 0.f);
    float v1 = fmaxf(acc[ii][1] + b1[gcol + 1], 0.f);
    float v2 = fmaxf(acc[ii][2] + b1[gcol + 2], 0.f);
    float v3 = fmaxf(acc[ii][3] + b1[gcol + 3], 0.f);
    ushort4 u;
    u.x = f2bf(v0); u.y = f2bf(v1); u.z = f2bf(v2); u.w = f2bf(v3);
    *(ushort4*)(h1 + (size_t)grow * F_HID + gcol) = u;
  }
}

// ---------------- GEMM2: z0 = h1 @ W2  (no bias), thread-per-row --------
__global__ __launch_bounds__(256) void gemm2(
    const __hip_bfloat16* __restrict__ h1, const float* __restrict__ W2,
    float* __restrict__ z0) {
  __shared__ float w2s[F_HID * F_OUT];  // 24 KB
  int t = threadIdx.x;
  for (int i = t; i < F_HID * F_OUT; i += 256) w2s[i] = W2[i];
  __syncthreads();
  int row = blockIdx.x * 256 + t;
  if (row >= N_NODES) return;
  const uint4* hp = reinterpret_cast<const uint4*>(h1 + (size_t)row * F_HID);
  float acc[F_OUT];
#pragma unroll
  for (int j = 0; j < F_OUT; ++j) acc[j] = 0.f;

  for (int kc = 0; kc < F_HID / 8; ++kc) {
    uint4 u = hp[kc];  // 8 bf16
    float a[8];
    a[0] = __uint_as_float(u.x << 16);
    a[1] = __uint_as_float(u.x & 0xffff0000u);
    a[2] = __uint_as_float(u.y << 16);
    a[3] = __uint_as_float(u.y & 0xffff0000u);
    a[4] = __uint_as_float(u.z << 16);
    a[5] = __uint_as_float(u.z & 0xffff0000u);
    a[6] = __uint_as_float(u.w << 16);
    a[7] = __uint_as_float(u.w & 0xffff0000u);
#pragma unroll
    for (int j = 0; j < 8; ++j) {
      int k = kc * 8 + j;
      const float4* w4 = (const float4*)&w2s[k * F_OUT];
      float4 b0 = w4[0], b1v = w4[1], b2v = w4[2];
      float4 b3 = w4[3], b4 = w4[4], b5 = w4[5];
      float av = a[j];
      acc[0] += av * b0.x;  acc[1] += av * b0.y;
      acc[2] += av * b0.z;  acc[3] += av * b0.w;
      acc[4] += av * b1v.x; acc[5] += av * b1v.y;
      acc[6] += av * b1v.z; acc[7] += av * b1v.w;
      acc[8] += av * b2v.x; acc[9] += av * b2v.y;
      acc[10] += av * b2v.z; acc[11] += av * b2v.w;
      acc[12] += av * b3.x; acc[13] += av * b3.y;
      acc[14] += av * b3.z; acc[15] += av * b3.w;
      acc[16] += av * b4.x; acc[17] += av * b4.y;
      acc[18] += av * b4.z; acc[19] += av * b4.w;
      acc[20] += av * b5.x; acc[21] += av * b5.y;
      acc[22] += av * b5.z; acc[23] += av * b5.w;
    }
  }
  float* zp = z0 + (size_t)row * F_OUT;
#pragma unroll
  for (int j = 0; j < F_OUT; ++j) zp[j] = acc[j];
}

// ---------------- scatter2: aggz[dst] += z0[src]  (24 floats/edge) ------
__global__ __launch_bounds__(256) void scatter24(
    const float* __restrict__ z0, const int* __restrict__ src,
    const int* __restrict__ dst, float* __restrict__ aggz) {
  int tid = blockIdx.x * 256 + threadIdx.x;
  int e = tid / 24;
  if (e >= N_EDGES) return;
  int c = tid - e * 24;
  atomicAdd(&aggz[(size_t)dst[e] * F_OUT + c], z0[(size_t)src[e] * F_OUT + c]);
}

// ---------------- finalize: out = log_softmax(z0 + aggz + b2) -----------
__global__ __launch_bounds__(256) void finalize(
    const float* __restrict__ z0, const float* __restrict__ aggz,
    const float* __restrict__ b2, float* __restrict__ out) {
  int row = blockIdx.x * 256 + threadIdx.x;
  if (row >= N_NODES) return;
  const float* zp = z0 + (size_t)row * F_OUT;
  const float* ap = aggz + (size_t)row * F_OUT;
  float v[F_OUT];
  float mx = -1e30f;
#pragma unroll
  for (int j = 0; j < F_OUT; ++j) {
    v[j] = zp[j] + ap[j] + b2[j];
    mx = fmaxf(mx, v[j]);
  }
  float se = 0.f;
#pragma unroll
  for (int j = 0; j < F_OUT; ++j) se += __expf(v[j] - mx);
  float lse = mx + __logf(se);
  float* op = out + (size_t)row * F_OUT;
#pragma unroll
  for (int j = 0; j < F_OUT; ++j) op[j] = v[j] - lse;
}

extern "C" void kernel_launch(void* const* d_in, const int* in_sizes, int n_in,
                              void* d_out, int out_size, void* d_ws,
                              size_t ws_size, hipStream_t stream) {
  const float* x = (const float*)d_in[0];
  const int* ei = (const int*)d_in[1];
  const float* W1 = (const float*)d_in[2];
  const float* b1 = (const float*)d_in[3];
  const float* W2 = (const float*)d_in[4];
  const float* b2 = (const float*)d_in[5];
  const int* src = ei;
  const int* dst = ei + N_EDGES;

  // workspace layout (bytes):
  //   agg1 : [0,          51,200,000)   f32 100000x128
  //   aggz : [51,200,000, 60,800,000)   f32 100000x24
  //   h1   : [60,800,000, 112,000,000)  bf16 100000x256
  //   z0   : [112,000,000,121,600,000)  f32 100000x24
  char* ws = (char*)d_ws;
  float* agg1 = (float*)ws;
  float* aggz = (float*)(ws + 51200000);
  __hip_bfloat16* h1 = (__hip_bfloat16*)(ws + 60800000);
  float* z0 = (float*)(ws + 112000000);
  float* out = (float*)d_out;

  // zero agg1 + aggz (contiguous 60.8 MB)
  zero_f4<<<2048, 256, 0, stream>>>((float4*)ws, 60800000 / 16);

  scatter128<<<(N_EDGES * 32 + 255) / 256, 256, 0, stream>>>(x, src, dst, agg1);

  dim3 g1(F_HID / 64, (N_NODES + 63) / 64);
  gemm1<<<g1, 256, 0, stream>>>(x, agg1, W1, b1, h1);

  gemm2<<<(N_NODES + 255) / 256, 256, 0, stream>>>(h1, W2, z0);

  scatter24<<<(N_EDGES * 24 + 255) / 256, 256, 0, stream>>>(z0, src, dst, aggz);

  finalize<<<(N_NODES + 255) / 256, 256, 0, stream>>>(z0, aggz, b2, out);
}

// Round 3
// 554.060 us; speedup vs baseline: 2.3549x; 2.3549x over previous
//
#include <hip/hip_runtime.h>
#include <hip/hip_bf16.h>
#include <math.h>

#define N_NODES 100000
#define N_EDGES 600000
#define F_IN 128
#define F_HID 256
#define F_OUT 24

// ---------------- CSR build: degree histogram ----------------
__global__ __launch_bounds__(256) void hist_deg(const int* __restrict__ dst,
                                                int* __restrict__ deg) {
  int e = blockIdx.x * 256 + threadIdx.x;
  if (e >= N_EDGES) return;
  atomicAdd(&deg[dst[e]], 1);
}

// ---------------- CSR build: exclusive prefix sum over 100k degrees ------
// Single block, 1024 threads, chunk of 98 elements each.
__global__ __launch_bounds__(1024) void scan_deg(const int* __restrict__ deg,
                                                 int* __restrict__ row_start) {
  __shared__ int part[1024];
  const int CH = (N_NODES + 1023) / 1024;  // 98
  int t = threadIdx.x;
  int base = t * CH;
  int end = min(base + CH, N_NODES);
  int s = 0;
  for (int i = base; i < end; ++i) s += deg[i];
  part[t] = s;
  __syncthreads();
  // Hillis-Steele inclusive scan in LDS
  for (int off = 1; off < 1024; off <<= 1) {
    int v = (t >= off) ? part[t - off] : 0;
    __syncthreads();
    part[t] += v;
    __syncthreads();
  }
  int run = (t > 0) ? part[t - 1] : 0;  // exclusive offset for this chunk
  for (int i = base; i < end; ++i) {
    row_start[i] = run;
    run += deg[i];
  }
}

// ---------------- CSR build: fill edge lists (sorted by dst) -------------
__global__ __launch_bounds__(256) void fill_csr(
    const int* __restrict__ src, const int* __restrict__ dst,
    const int* __restrict__ row_start, int* __restrict__ cursor,
    int* __restrict__ eidx) {
  int e = blockIdx.x * 256 + threadIdx.x;
  if (e >= N_EDGES) return;
  int d = dst[e];
  int pos = row_start[d] + atomicAdd(&cursor[d], 1);
  eidx[pos] = src[e];
}

// ---------------- layer-1 aggregate: h_pre[i] = x[i] + sum x[nbr] --------
// One wave (64 lanes) per node; each lane owns 2 columns (float2).
__global__ __launch_bounds__(256) void agg1_gather(
    const float* __restrict__ x, const int* __restrict__ row_start,
    const int* __restrict__ deg, const int* __restrict__ eidx,
    float* __restrict__ h_pre) {
  int wid = (blockIdx.x * 256 + threadIdx.x) >> 6;  // global wave id = node
  if (wid >= N_NODES) return;
  int lane = threadIdx.x & 63;
  int col = lane * 2;
  float2 acc = *(const float2*)(x + (size_t)wid * F_IN + col);  // self term
  int rs = row_start[wid];
  int dg = deg[wid];
  for (int j = 0; j < dg; ++j) {
    int s = eidx[rs + j];
    float2 v = *(const float2*)(x + (size_t)s * F_IN + col);
    acc.x += v.x;
    acc.y += v.y;
  }
  *(float2*)(h_pre + (size_t)wid * F_IN + col) = acc;
}

__device__ inline unsigned short f2bf(float f) {
  __hip_bfloat16 h = __float2bfloat16(f);
  return *reinterpret_cast<unsigned short*>(&h);
}

// ---------------- GEMM1: h1 = relu(h_pre @ W1 + b1), bf16 out -----------
// M=100000, K=128, N=256. 64x64 tile, BK=32, 256 threads, 4x4 per thread.
__global__ __launch_bounds__(256) void gemm1(
    const float* __restrict__ h_pre, const float* __restrict__ W1,
    const float* __restrict__ b1, __hip_bfloat16* __restrict__ h1) {
  __shared__ float As[32][64];  // [k][row]
  __shared__ float Bs[32][64];  // [k][col]
  int t = threadIdx.x;
  int tx = t & 15, ty = t >> 4;
  int row0 = blockIdx.y * 64, col0 = blockIdx.x * 64;
  float acc[4][4] = {{0.f}};

  for (int ko = 0; ko < F_IN; ko += 32) {
#pragma unroll
    for (int rep = 0; rep < 2; ++rep) {
      int i = t * 4 + rep * 1024;
      int r = i >> 5, ck = i & 31;
      int grow = row0 + r;
      float4 v = make_float4(0.f, 0.f, 0.f, 0.f);
      if (grow < N_NODES)
        v = *(const float4*)(h_pre + (size_t)grow * F_IN + ko + ck);
      As[ck + 0][r] = v.x;
      As[ck + 1][r] = v.y;
      As[ck + 2][r] = v.z;
      As[ck + 3][r] = v.w;
      int k = i >> 6, c2 = i & 63;
      *(float4*)&Bs[k][c2] =
          *(const float4*)(W1 + (size_t)(ko + k) * F_HID + col0 + c2);
    }
    __syncthreads();
#pragma unroll
    for (int k = 0; k < 32; ++k) {
      float4 a4 = *(const float4*)&As[k][ty * 4];
      float4 b4 = *(const float4*)&Bs[k][tx * 4];
      float a[4] = {a4.x, a4.y, a4.z, a4.w};
      float b[4] = {b4.x, b4.y, b4.z, b4.w};
#pragma unroll
      for (int ii = 0; ii < 4; ++ii)
#pragma unroll
        for (int jj = 0; jj < 4; ++jj) acc[ii][jj] += a[ii] * b[jj];
    }
    __syncthreads();
  }

#pragma unroll
  for (int ii = 0; ii < 4; ++ii) {
    int grow = row0 + ty * 4 + ii;
    if (grow >= N_NODES) break;
    int gcol = col0 + tx * 4;
    float v0 = fmaxf(acc[ii][0] + b1[gcol + 0], 0.f);
    float v1 = fmaxf(acc[ii][1] + b1[gcol + 1], 0.f);
    float v2 = fmaxf(acc[ii][2] + b1[gcol + 2], 0.f);
    float v3 = fmaxf(acc[ii][3] + b1[gcol + 3], 0.f);
    ushort4 u;
    u.x = f2bf(v0); u.y = f2bf(v1); u.z = f2bf(v2); u.w = f2bf(v3);
    *(ushort4*)(h1 + (size_t)grow * F_HID + gcol) = u;
  }
}

// ---------------- GEMM2: z0 = h1 @ W2  (no bias), thread-per-row --------
__global__ __launch_bounds__(256) void gemm2(
    const __hip_bfloat16* __restrict__ h1, const float* __restrict__ W2,
    float* __restrict__ z0) {
  __shared__ float w2s[F_HID * F_OUT];  // 24 KB
  int t = threadIdx.x;
  for (int i = t; i < F_HID * F_OUT; i += 256) w2s[i] = W2[i];
  __syncthreads();
  int row = blockIdx.x * 256 + t;
  if (row >= N_NODES) return;
  const uint4* hp = reinterpret_cast<const uint4*>(h1 + (size_t)row * F_HID);
  float acc[F_OUT];
#pragma unroll
  for (int j = 0; j < F_OUT; ++j) acc[j] = 0.f;

  for (int kc = 0; kc < F_HID / 8; ++kc) {
    uint4 u = hp[kc];  // 8 bf16
    float a[8];
    a[0] = __uint_as_float(u.x << 16);
    a[1] = __uint_as_float(u.x & 0xffff0000u);
    a[2] = __uint_as_float(u.y << 16);
    a[3] = __uint_as_float(u.y & 0xffff0000u);
    a[4] = __uint_as_float(u.z << 16);
    a[5] = __uint_as_float(u.z & 0xffff0000u);
    a[6] = __uint_as_float(u.w << 16);
    a[7] = __uint_as_float(u.w & 0xffff0000u);
#pragma unroll
    for (int j = 0; j < 8; ++j) {
      int k = kc * 8 + j;
      const float4* w4 = (const float4*)&w2s[k * F_OUT];
      float4 b0 = w4[0], b1v = w4[1], b2v = w4[2];
      float4 b3 = w4[3], b4 = w4[4], b5 = w4[5];
      float av = a[j];
      acc[0] += av * b0.x;  acc[1] += av * b0.y;
      acc[2] += av * b0.z;  acc[3] += av * b0.w;
      acc[4] += av * b1v.x; acc[5] += av * b1v.y;
      acc[6] += av * b1v.z; acc[7] += av * b1v.w;
      acc[8] += av * b2v.x; acc[9] += av * b2v.y;
      acc[10] += av * b2v.z; acc[11] += av * b2v.w;
      acc[12] += av * b3.x; acc[13] += av * b3.y;
      acc[14] += av * b3.z; acc[15] += av * b3.w;
      acc[16] += av * b4.x; acc[17] += av * b4.y;
      acc[18] += av * b4.z; acc[19] += av * b4.w;
      acc[20] += av * b5.x; acc[21] += av * b5.y;
      acc[22] += av * b5.z; acc[23] += av * b5.w;
    }
  }
  float* zp = z0 + (size_t)row * F_OUT;
#pragma unroll
  for (int j = 0; j < F_OUT; ++j) zp[j] = acc[j];
}

// ---------------- layer-2 aggregate + log_softmax, fused -----------------
// 32 lanes per node (24 active), 8 nodes per 256-block.
__global__ __launch_bounds__(256) void agg2_finalize(
    const float* __restrict__ z0, const int* __restrict__ row_start,
    const int* __restrict__ deg, const int* __restrict__ eidx,
    const float* __restrict__ b2, float* __restrict__ out) {
  int g = threadIdx.x >> 5;        // group 0..7
  int c = threadIdx.x & 31;        // lane-in-group
  int node = blockIdx.x * 8 + g;
  if (node >= N_NODES) return;
  bool act = (c < F_OUT);
  float v = 0.f;
  if (act) v = z0[(size_t)node * F_OUT + c] + b2[c];  // self + bias
  int rs = row_start[node];
  int dg = deg[node];
  for (int j = 0; j < dg; ++j) {
    int s = eidx[rs + j];
    if (act) v += z0[(size_t)s * F_OUT + c];
  }
  // max over 24 cols (width-32 butterfly; inactive lanes feed -inf)
  float mx = act ? v : -1e30f;
#pragma unroll
  for (int m = 16; m >= 1; m >>= 1) mx = fmaxf(mx, __shfl_xor(mx, m, 32));
  float e = act ? __expf(v - mx) : 0.f;
#pragma unroll
  for (int m = 16; m >= 1; m >>= 1) e += __shfl_xor(e, m, 32);
  float lse = mx + __logf(e);
  if (act) out[(size_t)node * F_OUT + c] = v - lse;
}

extern "C" void kernel_launch(void* const* d_in, const int* in_sizes, int n_in,
                              void* d_out, int out_size, void* d_ws,
                              size_t ws_size, hipStream_t stream) {
  const float* x = (const float*)d_in[0];
  const int* ei = (const int*)d_in[1];
  const float* W1 = (const float*)d_in[2];
  const float* b1 = (const float*)d_in[3];
  const float* W2 = (const float*)d_in[4];
  const float* b2 = (const float*)d_in[5];
  const int* src = ei;
  const int* dst = ei + N_EDGES;

  // workspace layout (bytes):
  //   deg       : [0,        400,000)
  //   cursor    : [400,000,  800,000)
  //   row_start : [800,000,  1,200,000)
  //   eidx      : [1,200,000,3,600,000)
  //   h_pre     : [3,600,000,54,800,000)    f32 100000x128
  //   h1        : [54,800,000,106,000,000)  bf16 100000x256
  //   z0        : [106,000,000,115,600,000) f32 100000x24
  char* ws = (char*)d_ws;
  int* deg = (int*)ws;
  int* cursor = (int*)(ws + 400000);
  int* row_start = (int*)(ws + 800000);
  int* eidx = (int*)(ws + 1200000);
  float* h_pre = (float*)(ws + 3600000);
  __hip_bfloat16* h1 = (__hip_bfloat16*)(ws + 54800000);
  float* z0 = (float*)(ws + 106000000);
  float* out = (float*)d_out;

  // zero deg + cursor (contiguous 800 KB)
  hipMemsetAsync(ws, 0, 800000, stream);

  const int EB = (N_EDGES + 255) / 256;
  hist_deg<<<EB, 256, 0, stream>>>(dst, deg);
  scan_deg<<<1, 1024, 0, stream>>>(deg, row_start);
  fill_csr<<<EB, 256, 0, stream>>>(src, dst, row_start, cursor, eidx);

  agg1_gather<<<(N_NODES * 64 + 255) / 256, 256, 0, stream>>>(
      x, row_start, deg, eidx, h_pre);

  dim3 g1(F_HID / 64, (N_NODES + 63) / 64);
  gemm1<<<g1, 256, 0, stream>>>(h_pre, W1, b1, h1);

  gemm2<<<(N_NODES + 255) / 256, 256, 0, stream>>>(h1, W2, z0);

  agg2_finalize<<<(N_NODES + 7) / 8, 256, 0, stream>>>(z0, row_start, deg,
                                                       eidx, b2, out);
}

// Round 4
// 409.987 us; speedup vs baseline: 3.1825x; 1.3514x over previous
//
#include <hip/hip_runtime.h>
#include <hip/hip_bf16.h>
#include <math.h>

#define N_NODES 100000
#define N_EDGES 600000
#define F_IN 128
#define F_HID 256
#define F_OUT 24
#define SCAN_NB 98  // ceil(100000/1024)

// ---------------- CSR build: degree histogram ----------------
__global__ __launch_bounds__(256) void hist_deg(const int* __restrict__ dst,
                                                int* __restrict__ deg) {
  int e = blockIdx.x * 256 + threadIdx.x;
  if (e >= N_EDGES) return;
  atomicAdd(&deg[dst[e]], 1);
}

// ---------------- multi-block exclusive scan, pass 1: block sums ---------
// 98 blocks x 256 threads, 4 elements/thread (1024/block).
__global__ __launch_bounds__(256) void scan_partial(
    const int* __restrict__ deg, int* __restrict__ blocksum) {
  int t = threadIdx.x;
  int base = blockIdx.x * 1024 + t * 4;
  int s = 0;
  if (base + 3 < N_NODES) {
    int4 v = *(const int4*)(deg + base);
    s = v.x + v.y + v.z + v.w;
  } else {
    for (int i = base; i < N_NODES; ++i) s += deg[i];
  }
  __shared__ int red[4];
#pragma unroll
  for (int off = 32; off >= 1; off >>= 1) s += __shfl_down(s, off, 64);
  if ((t & 63) == 0) red[t >> 6] = s;
  __syncthreads();
  if (t == 0) blocksum[blockIdx.x] = red[0] + red[1] + red[2] + red[3];
}

// ---------------- scan pass 2: exclusive scan of 98 block sums ----------
__global__ __launch_bounds__(128) void scan_blocksums(int* __restrict__ bs) {
  __shared__ int sh[128];
  int t = threadIdx.x;
  int v = (t < SCAN_NB) ? bs[t] : 0;
  sh[t] = v;
  __syncthreads();
  for (int off = 1; off < 128; off <<= 1) {
    int u = (t >= off) ? sh[t - off] : 0;
    __syncthreads();
    sh[t] += u;
    __syncthreads();
  }
  if (t < SCAN_NB) bs[t] = sh[t] - v;  // exclusive
}

// ---------------- scan pass 3: per-block exclusive + offset -------------
__global__ __launch_bounds__(256) void scan_final(
    const int* __restrict__ deg, const int* __restrict__ blocksum,
    int* __restrict__ row_start) {
  __shared__ int sh[256];
  int t = threadIdx.x;
  int base = blockIdx.x * 1024 + t * 4;
  int d[4] = {0, 0, 0, 0};
  if (base + 3 < N_NODES) {
    int4 v = *(const int4*)(deg + base);
    d[0] = v.x; d[1] = v.y; d[2] = v.z; d[3] = v.w;
  } else {
#pragma unroll
    for (int i = 0; i < 4; ++i)
      if (base + i < N_NODES) d[i] = deg[base + i];
  }
  int ts = d[0] + d[1] + d[2] + d[3];
  sh[t] = ts;
  __syncthreads();
  for (int off = 1; off < 256; off <<= 1) {
    int u = (t >= off) ? sh[t - off] : 0;
    __syncthreads();
    sh[t] += u;
    __syncthreads();
  }
  int run = blocksum[blockIdx.x] + sh[t] - ts;  // exclusive for this thread
#pragma unroll
  for (int i = 0; i < 4; ++i) {
    if (base + i < N_NODES) row_start[base + i] = run;
    run += d[i];
  }
}

// ---------------- CSR build: fill edge lists (sorted by dst) -------------
__global__ __launch_bounds__(256) void fill_csr(
    const int* __restrict__ src, const int* __restrict__ dst,
    const int* __restrict__ row_start, int* __restrict__ cursor,
    int* __restrict__ eidx) {
  int e = blockIdx.x * 256 + threadIdx.x;
  if (e >= N_EDGES) return;
  int d = dst[e];
  int pos = row_start[d] + atomicAdd(&cursor[d], 1);
  eidx[pos] = src[e];
}

// ---------------- layer-1 aggregate: h_pre[i] = x[i] + sum x[nbr] --------
// One wave (64 lanes) per node; each lane owns 2 columns (float2).
__global__ __launch_bounds__(256) void agg1_gather(
    const float* __restrict__ x, const int* __restrict__ row_start,
    const int* __restrict__ deg, const int* __restrict__ eidx,
    float* __restrict__ h_pre) {
  int wid = (blockIdx.x * 256 + threadIdx.x) >> 6;  // global wave id = node
  if (wid >= N_NODES) return;
  int lane = threadIdx.x & 63;
  int col = lane * 2;
  float2 acc = *(const float2*)(x + (size_t)wid * F_IN + col);  // self term
  int rs = row_start[wid];
  int dg = deg[wid];
  for (int j = 0; j < dg; ++j) {
    int s = eidx[rs + j];
    float2 v = *(const float2*)(x + (size_t)s * F_IN + col);
    acc.x += v.x;
    acc.y += v.y;
  }
  *(float2*)(h_pre + (size_t)wid * F_IN + col) = acc;
}

__device__ inline unsigned short f2bf(float f) {
  __hip_bfloat16 h = __float2bfloat16(f);
  return *reinterpret_cast<unsigned short*>(&h);
}

// ---------------- GEMM1: h1 = relu(h_pre @ W1 + b1), bf16 out -----------
// M=100000, K=128, N=256. 64x64 tile, BK=32, 256 threads, 4x4 per thread.
__global__ __launch_bounds__(256) void gemm1(
    const float* __restrict__ h_pre, const float* __restrict__ W1,
    const float* __restrict__ b1, __hip_bfloat16* __restrict__ h1) {
  __shared__ float As[32][64];  // [k][row]
  __shared__ float Bs[32][64];  // [k][col]
  int t = threadIdx.x;
  int tx = t & 15, ty = t >> 4;
  int row0 = blockIdx.y * 64, col0 = blockIdx.x * 64;
  float acc[4][4] = {{0.f}};

  for (int ko = 0; ko < F_IN; ko += 32) {
#pragma unroll
    for (int rep = 0; rep < 2; ++rep) {
      int i = t * 4 + rep * 1024;
      int r = i >> 5, ck = i & 31;
      int grow = row0 + r;
      float4 v = make_float4(0.f, 0.f, 0.f, 0.f);
      if (grow < N_NODES)
        v = *(const float4*)(h_pre + (size_t)grow * F_IN + ko + ck);
      As[ck + 0][r] = v.x;
      As[ck + 1][r] = v.y;
      As[ck + 2][r] = v.z;
      As[ck + 3][r] = v.w;
      int k = i >> 6, c2 = i & 63;
      *(float4*)&Bs[k][c2] =
          *(const float4*)(W1 + (size_t)(ko + k) * F_HID + col0 + c2);
    }
    __syncthreads();
#pragma unroll
    for (int k = 0; k < 32; ++k) {
      float4 a4 = *(const float4*)&As[k][ty * 4];
      float4 b4 = *(const float4*)&Bs[k][tx * 4];
      float a[4] = {a4.x, a4.y, a4.z, a4.w};
      float b[4] = {b4.x, b4.y, b4.z, b4.w};
#pragma unroll
      for (int ii = 0; ii < 4; ++ii)
#pragma unroll
        for (int jj = 0; jj < 4; ++jj) acc[ii][jj] += a[ii] * b[jj];
    }
    __syncthreads();
  }

#pragma unroll
  for (int ii = 0; ii < 4; ++ii) {
    int grow = row0 + ty * 4 + ii;
    if (grow >= N_NODES) break;
    int gcol = col0 + tx * 4;
    float v0 = fmaxf(acc[ii][0] + b1[gcol + 0], 0.f);
    float v1 = fmaxf(acc[ii][1] + b1[gcol + 1], 0.f);
    float v2 = fmaxf(acc[ii][2] + b1[gcol + 2], 0.f);
    float v3 = fmaxf(acc[ii][3] + b1[gcol + 3], 0.f);
    ushort4 u;
    u.x = f2bf(v0); u.y = f2bf(v1); u.z = f2bf(v2); u.w = f2bf(v3);
    *(ushort4*)(h1 + (size_t)grow * F_HID + gcol) = u;
  }
}

// ---------------- GEMM2: z0 = h1 @ W2  (no bias), thread-per-row --------
__global__ __launch_bounds__(256) void gemm2(
    const __hip_bfloat16* __restrict__ h1, const float* __restrict__ W2,
    float* __restrict__ z0) {
  __shared__ float w2s[F_HID * F_OUT];  // 24 KB
  int t = threadIdx.x;
  for (int i = t; i < F_HID * F_OUT; i += 256) w2s[i] = W2[i];
  __syncthreads();
  int row = blockIdx.x * 256 + t;
  if (row >= N_NODES) return;
  const uint4* hp = reinterpret_cast<const uint4*>(h1 + (size_t)row * F_HID);
  float acc[F_OUT];
#pragma unroll
  for (int j = 0; j < F_OUT; ++j) acc[j] = 0.f;

  for (int kc = 0; kc < F_HID / 8; ++kc) {
    uint4 u = hp[kc];  // 8 bf16
    float a[8];
    a[0] = __uint_as_float(u.x << 16);
    a[1] = __uint_as_float(u.x & 0xffff0000u);
    a[2] = __uint_as_float(u.y << 16);
    a[3] = __uint_as_float(u.y & 0xffff0000u);
    a[4] = __uint_as_float(u.z << 16);
    a[5] = __uint_as_float(u.z & 0xffff0000u);
    a[6] = __uint_as_float(u.w << 16);
    a[7] = __uint_as_float(u.w & 0xffff0000u);
#pragma unroll
    for (int j = 0; j < 8; ++j) {
      int k = kc * 8 + j;
      const float4* w4 = (const float4*)&w2s[k * F_OUT];
      float4 b0 = w4[0], b1v = w4[1], b2v = w4[2];
      float4 b3 = w4[3], b4 = w4[4], b5 = w4[5];
      float av = a[j];
      acc[0] += av * b0.x;  acc[1] += av * b0.y;
      acc[2] += av * b0.z;  acc[3] += av * b0.w;
      acc[4] += av * b1v.x; acc[5] += av * b1v.y;
      acc[6] += av * b1v.z; acc[7] += av * b1v.w;
      acc[8] += av * b2v.x; acc[9] += av * b2v.y;
      acc[10] += av * b2v.z; acc[11] += av * b2v.w;
      acc[12] += av * b3.x; acc[13] += av * b3.y;
      acc[14] += av * b3.z; acc[15] += av * b3.w;
      acc[16] += av * b4.x; acc[17] += av * b4.y;
      acc[18] += av * b4.z; acc[19] += av * b4.w;
      acc[20] += av * b5.x; acc[21] += av * b5.y;
      acc[22] += av * b5.z; acc[23] += av * b5.w;
    }
  }
  float* zp = z0 + (size_t)row * F_OUT;
#pragma unroll
  for (int j = 0; j < F_OUT; ++j) zp[j] = acc[j];
}

// ---------------- layer-2 aggregate + log_softmax, fused -----------------
// 32 lanes per node (24 active), 8 nodes per 256-block.
__global__ __launch_bounds__(256) void agg2_finalize(
    const float* __restrict__ z0, const int* __restrict__ row_start,
    const int* __restrict__ deg, const int* __restrict__ eidx,
    const float* __restrict__ b2, float* __restrict__ out) {
  int g = threadIdx.x >> 5;        // group 0..7
  int c = threadIdx.x & 31;        // lane-in-group
  int node = blockIdx.x * 8 + g;
  if (node >= N_NODES) return;
  bool act = (c < F_OUT);
  float v = 0.f;
  if (act) v = z0[(size_t)node * F_OUT + c] + b2[c];  // self + bias
  int rs = row_start[node];
  int dg = deg[node];
  for (int j = 0; j < dg; ++j) {
    int s = eidx[rs + j];
    if (act) v += z0[(size_t)s * F_OUT + c];
  }
  // max over 24 cols (width-32 butterfly; inactive lanes feed -inf)
  float mx = act ? v : -1e30f;
#pragma unroll
  for (int m = 16; m >= 1; m >>= 1) mx = fmaxf(mx, __shfl_xor(mx, m, 32));
  float e = act ? __expf(v - mx) : 0.f;
#pragma unroll
  for (int m = 16; m >= 1; m >>= 1) e += __shfl_xor(e, m, 32);
  float lse = mx + __logf(e);
  if (act) out[(size_t)node * F_OUT + c] = v - lse;
}

extern "C" void kernel_launch(void* const* d_in, const int* in_sizes, int n_in,
                              void* d_out, int out_size, void* d_ws,
                              size_t ws_size, hipStream_t stream) {
  const float* x = (const float*)d_in[0];
  const int* ei = (const int*)d_in[1];
  const float* W1 = (const float*)d_in[2];
  const float* b1 = (const float*)d_in[3];
  const float* W2 = (const float*)d_in[4];
  const float* b2 = (const float*)d_in[5];
  const int* src = ei;
  const int* dst = ei + N_EDGES;

  // workspace layout (bytes):
  //   deg       : [0,        400,000)
  //   cursor    : [400,000,  800,000)
  //   row_start : [800,000,  1,200,000)
  //   eidx      : [1,200,000,3,600,000)
  //   h_pre     : [3,600,000,54,800,000)    f32 100000x128
  //   h1        : [54,800,000,106,000,000)  bf16 100000x256
  //   z0        : [106,000,000,115,600,000) f32 100000x24
  //   blocksum  : [115,600,000,115,600,392) int 98
  char* ws = (char*)d_ws;
  int* deg = (int*)ws;
  int* cursor = (int*)(ws + 400000);
  int* row_start = (int*)(ws + 800000);
  int* eidx = (int*)(ws + 1200000);
  float* h_pre = (float*)(ws + 3600000);
  __hip_bfloat16* h1 = (__hip_bfloat16*)(ws + 54800000);
  float* z0 = (float*)(ws + 106000000);
  int* blocksum = (int*)(ws + 115600000);
  float* out = (float*)d_out;

  // zero deg + cursor (contiguous 800 KB)
  hipMemsetAsync(ws, 0, 800000, stream);

  const int EB = (N_EDGES + 255) / 256;
  hist_deg<<<EB, 256, 0, stream>>>(dst, deg);

  scan_partial<<<SCAN_NB, 256, 0, stream>>>(deg, blocksum);
  scan_blocksums<<<1, 128, 0, stream>>>(blocksum);
  scan_final<<<SCAN_NB, 256, 0, stream>>>(deg, blocksum, row_start);

  fill_csr<<<EB, 256, 0, stream>>>(src, dst, row_start, cursor, eidx);

  agg1_gather<<<(N_NODES * 64 + 255) / 256, 256, 0, stream>>>(
      x, row_start, deg, eidx, h_pre);

  dim3 g1(F_HID / 64, (N_NODES + 63) / 64);
  gemm1<<<g1, 256, 0, stream>>>(h_pre, W1, b1, h1);

  gemm2<<<(N_NODES + 255) / 256, 256, 0, stream>>>(h1, W2, z0);

  agg2_finalize<<<(N_NODES + 7) / 8, 256, 0, stream>>>(z0, row_start, deg,
                                                       eidx, b2, out);
}

// Round 5
// 348.991 us; speedup vs baseline: 3.7387x; 1.1748x over previous
//
#include <hip/hip_runtime.h>
#include <hip/hip_bf16.h>
#include <math.h>

#define N_NODES 100000
#define N_EDGES 600000
#define F_IN 128
#define F_HID 256
#define F_OUT 24
#define SCAN_NB 98  // ceil(100000/1024)

typedef __attribute__((ext_vector_type(8))) short bf16x8;
typedef __attribute__((ext_vector_type(4))) float f32x4;

// ---------------- CSR build: degree histogram ----------------
__global__ __launch_bounds__(256) void hist_deg(const int* __restrict__ dst,
                                                int* __restrict__ deg) {
  int e = blockIdx.x * 256 + threadIdx.x;
  if (e >= N_EDGES) return;
  atomicAdd(&deg[dst[e]], 1);
}

// ---------------- multi-block exclusive scan, pass 1: block sums ---------
__global__ __launch_bounds__(256) void scan_partial(
    const int* __restrict__ deg, int* __restrict__ blocksum) {
  int t = threadIdx.x;
  int base = blockIdx.x * 1024 + t * 4;
  int s = 0;
  if (base + 3 < N_NODES) {
    int4 v = *(const int4*)(deg + base);
    s = v.x + v.y + v.z + v.w;
  } else {
    for (int i = base; i < N_NODES; ++i) s += deg[i];
  }
  __shared__ int red[4];
#pragma unroll
  for (int off = 32; off >= 1; off >>= 1) s += __shfl_down(s, off, 64);
  if ((t & 63) == 0) red[t >> 6] = s;
  __syncthreads();
  if (t == 0) blocksum[blockIdx.x] = red[0] + red[1] + red[2] + red[3];
}

// ---------------- scan pass 2: exclusive scan of 98 block sums ----------
__global__ __launch_bounds__(128) void scan_blocksums(int* __restrict__ bs) {
  __shared__ int sh[128];
  int t = threadIdx.x;
  int v = (t < SCAN_NB) ? bs[t] : 0;
  sh[t] = v;
  __syncthreads();
  for (int off = 1; off < 128; off <<= 1) {
    int u = (t >= off) ? sh[t - off] : 0;
    __syncthreads();
    sh[t] += u;
    __syncthreads();
  }
  if (t < SCAN_NB) bs[t] = sh[t] - v;  // exclusive
}

// ---------------- scan pass 3: per-block exclusive + offset -------------
__global__ __launch_bounds__(256) void scan_final(
    const int* __restrict__ deg, const int* __restrict__ blocksum,
    int* __restrict__ row_start) {
  __shared__ int sh[256];
  int t = threadIdx.x;
  int base = blockIdx.x * 1024 + t * 4;
  int d[4] = {0, 0, 0, 0};
  if (base + 3 < N_NODES) {
    int4 v = *(const int4*)(deg + base);
    d[0] = v.x; d[1] = v.y; d[2] = v.z; d[3] = v.w;
  } else {
#pragma unroll
    for (int i = 0; i < 4; ++i)
      if (base + i < N_NODES) d[i] = deg[base + i];
  }
  int ts = d[0] + d[1] + d[2] + d[3];
  sh[t] = ts;
  __syncthreads();
  for (int off = 1; off < 256; off <<= 1) {
    int u = (t >= off) ? sh[t - off] : 0;
    __syncthreads();
    sh[t] += u;
    __syncthreads();
  }
  int run = blocksum[blockIdx.x] + sh[t] - ts;
#pragma unroll
  for (int i = 0; i < 4; ++i) {
    if (base + i < N_NODES) row_start[base + i] = run;
    run += d[i];
  }
}

// ---------------- CSR build: fill edge lists (sorted by dst) -------------
__global__ __launch_bounds__(256) void fill_csr(
    const int* __restrict__ src, const int* __restrict__ dst,
    const int* __restrict__ row_start, int* __restrict__ cursor,
    int* __restrict__ eidx) {
  int e = blockIdx.x * 256 + threadIdx.x;
  if (e >= N_EDGES) return;
  int d = dst[e];
  int pos = row_start[d] + atomicAdd(&cursor[d], 1);
  eidx[pos] = src[e];
}

__device__ inline unsigned short f2bf(float f) {
  __hip_bfloat16 h = __float2bfloat16(f);
  return *reinterpret_cast<unsigned short*>(&h);
}

// ---------------- layer-1 aggregate: h_pre[i] = x[i] + sum x[nbr] --------
// One wave per node; lane owns 2 cols. f32 accumulate, bf16 store.
__global__ __launch_bounds__(256) void agg1_gather(
    const float* __restrict__ x, const int* __restrict__ row_start,
    const int* __restrict__ deg, const int* __restrict__ eidx,
    unsigned short* __restrict__ h_pre) {
  int wid = (blockIdx.x * 256 + threadIdx.x) >> 6;
  if (wid >= N_NODES) return;
  int lane = threadIdx.x & 63;
  int col = lane * 2;
  float2 acc = *(const float2*)(x + (size_t)wid * F_IN + col);  // self
  int rs = row_start[wid];
  int dg = deg[wid];
  for (int j = 0; j < dg; ++j) {
    int s = eidx[rs + j];
    float2 v = *(const float2*)(x + (size_t)s * F_IN + col);
    acc.x += v.x;
    acc.y += v.y;
  }
  ushort2 o;
  o.x = f2bf(acc.x);
  o.y = f2bf(acc.y);
  *(ushort2*)(h_pre + (size_t)wid * F_IN + col) = o;
}

// ---------------- prep: w1t[n][k] = bf16(W1[k][n])  (256x128) -----------
__global__ __launch_bounds__(256) void prep_w1t(
    const float* __restrict__ W1, unsigned short* __restrict__ w1t) {
  int i = blockIdx.x * 256 + threadIdx.x;  // = n*128 + k
  if (i >= F_IN * F_HID) return;
  int n = i >> 7, k = i & 127;
  w1t[i] = f2bf(W1[k * F_HID + n]);
}

// ---------------- GEMM1 (MFMA): h1 = relu(h_pre @ W1 + b1), bf16 --------
// M=100000, K=128 (whole K in regs), N=256. Block tile 64x256, 4 waves;
// wave w owns 64-col quadrant. A staged in LDS with XOR swizzle (G4).
__global__ __launch_bounds__(256) void gemm1_mfma(
    const unsigned short* __restrict__ hpre,  // bf16 [N_NODES][128]
    const unsigned short* __restrict__ w1t,   // bf16 [256][128]
    const float* __restrict__ b1, __hip_bfloat16* __restrict__ h1) {
  __shared__ unsigned char Asm[64 * 128 * 2];  // 16 KB, swizzled
  int t = threadIdx.x;
  int lane = t & 63;
  int w = t >> 6;  // wave -> col quadrant
  int m0 = blockIdx.x * 64;

  // stage A tile 64x128 bf16: 1024 x 16B chunks, swizzled dest
  for (int ci = t; ci < 1024; ci += 256) {
    int r = ci >> 4;    // row 0..63
    int c8 = ci & 15;   // 16B chunk within row
    int gr = m0 + r;
    uint4 v = make_uint4(0, 0, 0, 0);
    if (gr < N_NODES) v = *(const uint4*)(hpre + (size_t)gr * F_IN + c8 * 8);
    int byte = (r * 256 + c8 * 16) ^ ((r & 7) << 4);
    *(uint4*)(Asm + byte) = v;
  }

  // B fragments: wave's 64 cols x whole K, from L2-resident w1t
  int fl = lane & 15;          // frag row/col index
  int fk = (lane >> 4) * 8;    // k base within 32-slice
  bf16x8 bfrag[4][4];          // [nt][ks]
#pragma unroll
  for (int nt = 0; nt < 4; ++nt)
#pragma unroll
    for (int ks = 0; ks < 4; ++ks)
      bfrag[nt][ks] = *(const bf16x8*)(
          w1t + (size_t)(w * 64 + nt * 16 + fl) * F_IN + ks * 32 + fk);

  __syncthreads();

  f32x4 acc[4][4];  // [mt][nt]
#pragma unroll
  for (int mt = 0; mt < 4; ++mt)
#pragma unroll
    for (int nt = 0; nt < 4; ++nt) acc[mt][nt] = f32x4{0.f, 0.f, 0.f, 0.f};

#pragma unroll
  for (int mt = 0; mt < 4; ++mt) {
    bf16x8 afrag[4];
#pragma unroll
    for (int ks = 0; ks < 4; ++ks) {
      int r = mt * 16 + fl;
      int byte = (r * 256 + (ks * 32 + fk) * 2) ^ ((r & 7) << 4);
      afrag[ks] = *(const bf16x8*)(Asm + byte);
    }
#pragma unroll
    for (int nt = 0; nt < 4; ++nt)
#pragma unroll
      for (int ks = 0; ks < 4; ++ks)
        acc[mt][nt] = __builtin_amdgcn_mfma_f32_16x16x32_bf16(
            afrag[ks], bfrag[nt][ks], acc[mt][nt], 0, 0, 0);
  }

  // epilogue: C/D layout col=lane&15, row=(lane>>4)*4+j  (m89)
  int rb = (lane >> 4) * 4;
#pragma unroll
  for (int mt = 0; mt < 4; ++mt) {
#pragma unroll
    for (int nt = 0; nt < 4; ++nt) {
      int gcol = w * 64 + nt * 16 + fl;
      float bias = b1[gcol];
#pragma unroll
      for (int j = 0; j < 4; ++j) {
        int grow = m0 + mt * 16 + rb + j;
        if (grow < N_NODES) {
          float v = fmaxf(acc[mt][nt][j] + bias, 0.f);
          h1[(size_t)grow * F_HID + gcol] = __float2bfloat16(v);
        }
      }
    }
  }
}

// ---------------- GEMM2: z0 = h1 @ W2  (no bias), thread-per-row --------
__global__ __launch_bounds__(256) void gemm2(
    const __hip_bfloat16* __restrict__ h1, const float* __restrict__ W2,
    float* __restrict__ z0) {
  __shared__ float w2s[F_HID * F_OUT];  // 24 KB
  int t = threadIdx.x;
  for (int i = t; i < F_HID * F_OUT; i += 256) w2s[i] = W2[i];
  __syncthreads();
  int row = blockIdx.x * 256 + t;
  if (row >= N_NODES) return;
  const uint4* hp = reinterpret_cast<const uint4*>(h1 + (size_t)row * F_HID);
  float acc[F_OUT];
#pragma unroll
  for (int j = 0; j < F_OUT; ++j) acc[j] = 0.f;

  for (int kc = 0; kc < F_HID / 8; ++kc) {
    uint4 u = hp[kc];  // 8 bf16
    float a[8];
    a[0] = __uint_as_float(u.x << 16);
    a[1] = __uint_as_float(u.x & 0xffff0000u);
    a[2] = __uint_as_float(u.y << 16);
    a[3] = __uint_as_float(u.y & 0xffff0000u);
    a[4] = __uint_as_float(u.z << 16);
    a[5] = __uint_as_float(u.z & 0xffff0000u);
    a[6] = __uint_as_float(u.w << 16);
    a[7] = __uint_as_float(u.w & 0xffff0000u);
#pragma unroll
    for (int j = 0; j < 8; ++j) {
      int k = kc * 8 + j;
      const float4* w4 = (const float4*)&w2s[k * F_OUT];
      float4 b0 = w4[0], b1v = w4[1], b2v = w4[2];
      float4 b3 = w4[3], b4 = w4[4], b5 = w4[5];
      float av = a[j];
      acc[0] += av * b0.x;  acc[1] += av * b0.y;
      acc[2] += av * b0.z;  acc[3] += av * b0.w;
      acc[4] += av * b1v.x; acc[5] += av * b1v.y;
      acc[6] += av * b1v.z; acc[7] += av * b1v.w;
      acc[8] += av * b2v.x; acc[9] += av * b2v.y;
      acc[10] += av * b2v.z; acc[11] += av * b2v.w;
      acc[12] += av * b3.x; acc[13] += av * b3.y;
      acc[14] += av * b3.z; acc[15] += av * b3.w;
      acc[16] += av * b4.x; acc[17] += av * b4.y;
      acc[18] += av * b4.z; acc[19] += av * b4.w;
      acc[20] += av * b5.x; acc[21] += av * b5.y;
      acc[22] += av * b5.z; acc[23] += av * b5.w;
    }
  }
  float* zp = z0 + (size_t)row * F_OUT;
#pragma unroll
  for (int j = 0; j < F_OUT; ++j) zp[j] = acc[j];
}

// ---------------- layer-2 aggregate + log_softmax, fused -----------------
__global__ __launch_bounds__(256) void agg2_finalize(
    const float* __restrict__ z0, const int* __restrict__ row_start,
    const int* __restrict__ deg, const int* __restrict__ eidx,
    const float* __restrict__ b2, float* __restrict__ out) {
  int g = threadIdx.x >> 5;
  int c = threadIdx.x & 31;
  int node = blockIdx.x * 8 + g;
  if (node >= N_NODES) return;
  bool act = (c < F_OUT);
  float v = 0.f;
  if (act) v = z0[(size_t)node * F_OUT + c] + b2[c];
  int rs = row_start[node];
  int dg = deg[node];
  for (int j = 0; j < dg; ++j) {
    int s = eidx[rs + j];
    if (act) v += z0[(size_t)s * F_OUT + c];
  }
  float mx = act ? v : -1e30f;
#pragma unroll
  for (int m = 16; m >= 1; m >>= 1) mx = fmaxf(mx, __shfl_xor(mx, m, 32));
  float e = act ? __expf(v - mx) : 0.f;
#pragma unroll
  for (int m = 16; m >= 1; m >>= 1) e += __shfl_xor(e, m, 32);
  float lse = mx + __logf(e);
  if (act) out[(size_t)node * F_OUT + c] = v - lse;
}

extern "C" void kernel_launch(void* const* d_in, const int* in_sizes, int n_in,
                              void* d_out, int out_size, void* d_ws,
                              size_t ws_size, hipStream_t stream) {
  const float* x = (const float*)d_in[0];
  const int* ei = (const int*)d_in[1];
  const float* W1 = (const float*)d_in[2];
  const float* b1 = (const float*)d_in[3];
  const float* W2 = (const float*)d_in[4];
  const float* b2 = (const float*)d_in[5];
  const int* src = ei;
  const int* dst = ei + N_EDGES;

  // workspace layout (bytes):
  //   deg       : [0,          400,000)
  //   cursor    : [400,000,    800,000)
  //   row_start : [800,000,  1,200,000)
  //   eidx      : [1,200,000, 3,600,000)
  //   h_pre     : [3,600,000, 29,200,000)   bf16 100000x128
  //   h1        : [29,200,000, 80,400,000)  bf16 100000x256
  //   z0        : [80,400,000, 90,000,000)  f32 100000x24
  //   blocksum  : [90,000,000, 90,000,392)  int 98
  //   w1t       : [90,000,400, 90,065,936)  bf16 256x128
  char* ws = (char*)d_ws;
  int* deg = (int*)ws;
  int* cursor = (int*)(ws + 400000);
  int* row_start = (int*)(ws + 800000);
  int* eidx = (int*)(ws + 1200000);
  unsigned short* h_pre = (unsigned short*)(ws + 3600000);
  __hip_bfloat16* h1 = (__hip_bfloat16*)(ws + 29200000);
  float* z0 = (float*)(ws + 80400000);
  int* blocksum = (int*)(ws + 90000000);
  unsigned short* w1t = (unsigned short*)(ws + 90000400);
  float* out = (float*)d_out;

  // zero deg + cursor (contiguous 800 KB)
  hipMemsetAsync(ws, 0, 800000, stream);

  const int EB = (N_EDGES + 255) / 256;
  hist_deg<<<EB, 256, 0, stream>>>(dst, deg);

  scan_partial<<<SCAN_NB, 256, 0, stream>>>(deg, blocksum);
  scan_blocksums<<<1, 128, 0, stream>>>(blocksum);
  scan_final<<<SCAN_NB, 256, 0, stream>>>(deg, blocksum, row_start);

  fill_csr<<<EB, 256, 0, stream>>>(src, dst, row_start, cursor, eidx);

  prep_w1t<<<(F_IN * F_HID + 255) / 256, 256, 0, stream>>>(W1, w1t);

  agg1_gather<<<(N_NODES * 64 + 255) / 256, 256, 0, stream>>>(
      x, row_start, deg, eidx, h_pre);

  gemm1_mfma<<<(N_NODES + 63) / 64, 256, 0, stream>>>(h_pre, w1t, b1, h1);

  gemm2<<<(N_NODES + 255) / 256, 256, 0, stream>>>(h1, W2, z0);

  agg2_finalize<<<(N_NODES + 7) / 8, 256, 0, stream>>>(z0, row_start, deg,
                                                       eidx, b2, out);
}

// Round 6
// 293.481 us; speedup vs baseline: 4.4459x; 1.1891x over previous
//
#include <hip/hip_runtime.h>
#include <hip/hip_bf16.h>
#include <math.h>

#define N_NODES 100000
#define N_EDGES 600000
#define F_IN 128
#define F_HID 256
#define F_OUT 24
#define SCAN_NB 98  // ceil(100000/1024)

typedef __attribute__((ext_vector_type(8))) short bf16x8;
typedef __attribute__((ext_vector_type(4))) float f32x4;

__device__ inline unsigned short f2bf(float f) {
  __hip_bfloat16 h = __float2bfloat16(f);
  return *reinterpret_cast<unsigned short*>(&h);
}
__device__ inline float bf2f(unsigned short u) {
  return __uint_as_float(((unsigned int)u) << 16);
}

// ---------------- CSR build: degree histogram ----------------
__global__ __launch_bounds__(256) void hist_deg(const int* __restrict__ dst,
                                                int* __restrict__ deg) {
  int e = blockIdx.x * 256 + threadIdx.x;
  if (e >= N_EDGES) return;
  atomicAdd(&deg[dst[e]], 1);
}

// ---------------- multi-block exclusive scan, pass 1: block sums ---------
__global__ __launch_bounds__(256) void scan_partial(
    const int* __restrict__ deg, int* __restrict__ blocksum) {
  int t = threadIdx.x;
  int base = blockIdx.x * 1024 + t * 4;
  int s = 0;
  if (base + 3 < N_NODES) {
    int4 v = *(const int4*)(deg + base);
    s = v.x + v.y + v.z + v.w;
  } else {
    for (int i = base; i < N_NODES; ++i) s += deg[i];
  }
  __shared__ int red[4];
#pragma unroll
  for (int off = 32; off >= 1; off >>= 1) s += __shfl_down(s, off, 64);
  if ((t & 63) == 0) red[t >> 6] = s;
  __syncthreads();
  if (t == 0) blocksum[blockIdx.x] = red[0] + red[1] + red[2] + red[3];
}

// ---------------- scan pass 2: exclusive scan of 98 block sums ----------
__global__ __launch_bounds__(128) void scan_blocksums(int* __restrict__ bs) {
  __shared__ int sh[128];
  int t = threadIdx.x;
  int v = (t < SCAN_NB) ? bs[t] : 0;
  sh[t] = v;
  __syncthreads();
  for (int off = 1; off < 128; off <<= 1) {
    int u = (t >= off) ? sh[t - off] : 0;
    __syncthreads();
    sh[t] += u;
    __syncthreads();
  }
  if (t < SCAN_NB) bs[t] = sh[t] - v;  // exclusive
}

// ---------------- scan pass 3: per-block exclusive + offset -------------
__global__ __launch_bounds__(256) void scan_final(
    const int* __restrict__ deg, const int* __restrict__ blocksum,
    int* __restrict__ row_start) {
  __shared__ int sh[256];
  int t = threadIdx.x;
  int base = blockIdx.x * 1024 + t * 4;
  int d[4] = {0, 0, 0, 0};
  if (base + 3 < N_NODES) {
    int4 v = *(const int4*)(deg + base);
    d[0] = v.x; d[1] = v.y; d[2] = v.z; d[3] = v.w;
  } else {
#pragma unroll
    for (int i = 0; i < 4; ++i)
      if (base + i < N_NODES) d[i] = deg[base + i];
  }
  int ts = d[0] + d[1] + d[2] + d[3];
  sh[t] = ts;
  __syncthreads();
  for (int off = 1; off < 256; off <<= 1) {
    int u = (t >= off) ? sh[t - off] : 0;
    __syncthreads();
    sh[t] += u;
    __syncthreads();
  }
  int run = blocksum[blockIdx.x] + sh[t] - ts;
#pragma unroll
  for (int i = 0; i < 4; ++i) {
    if (base + i < N_NODES) row_start[base + i] = run;
    run += d[i];
  }
}

// ---------------- CSR build: fill edge lists (sorted by dst) -------------
__global__ __launch_bounds__(256) void fill_csr(
    const int* __restrict__ src, const int* __restrict__ dst,
    const int* __restrict__ row_start, int* __restrict__ cursor,
    int* __restrict__ eidx) {
  int e = blockIdx.x * 256 + threadIdx.x;
  if (e >= N_EDGES) return;
  int d = dst[e];
  int pos = row_start[d] + atomicAdd(&cursor[d], 1);
  eidx[pos] = src[e];
}

// ---------------- prep: xb = bf16(x), 8 elems/thread streaming ----------
__global__ __launch_bounds__(256) void prep_xbf(
    const float* __restrict__ x, unsigned int* __restrict__ xb) {
  const int n8 = N_NODES * F_IN / 8;  // 1.6M
  int i = blockIdx.x * 256 + threadIdx.x;
  int stride = gridDim.x * 256;
  for (; i < n8; i += stride) {
    float4 a = ((const float4*)x)[i * 2];
    float4 b = ((const float4*)x)[i * 2 + 1];
    uint4 o;
    o.x = (unsigned)f2bf(a.x) | ((unsigned)f2bf(a.y) << 16);
    o.y = (unsigned)f2bf(a.z) | ((unsigned)f2bf(a.w) << 16);
    o.z = (unsigned)f2bf(b.x) | ((unsigned)f2bf(b.y) << 16);
    o.w = (unsigned)f2bf(b.z) | ((unsigned)f2bf(b.w) << 16);
    ((uint4*)xb)[i] = o;
  }
}

// ---------------- prep: w1t[n][k] = bf16(W1[k][n])  (256x128) -----------
__global__ __launch_bounds__(256) void prep_w1t(
    const float* __restrict__ W1, unsigned short* __restrict__ w1t) {
  int i = blockIdx.x * 256 + threadIdx.x;  // = n*128 + k
  if (i >= F_IN * F_HID) return;
  int n = i >> 7, k = i & 127;
  w1t[i] = f2bf(W1[k * F_HID + n]);
}

// ---------------- layer-1 aggregate (bf16 gather, index-pipelined) ------
// 32-lane group per node; lane owns 4 cols (8B). Indices preloaded into
// lanes, shfl-broadcast, gathers issued in batches of 4 (MLP).
__global__ __launch_bounds__(256) void agg1_gather(
    const unsigned short* __restrict__ xb, const int* __restrict__ row_start,
    const int* __restrict__ deg, const int* __restrict__ eidx,
    unsigned short* __restrict__ h_pre) {
  int g = threadIdx.x >> 5;
  int l = threadIdx.x & 31;
  int node = blockIdx.x * 8 + g;
  if (node >= N_NODES) return;
  int col = l * 4;

  ushort4 sv = *(const ushort4*)(xb + (size_t)node * F_IN + col);  // self
  float a0 = bf2f(sv.x), a1 = bf2f(sv.y), a2 = bf2f(sv.z), a3 = bf2f(sv.w);

  int rs = row_start[node];
  int dg = deg[node];
  for (int base = 0; base < dg; base += 32) {
    int cnt = min(32, dg - base);
    int myidx = (l < cnt) ? eidx[rs + base + l] : 0;
    int j = 0;
    for (; j + 4 <= cnt; j += 4) {
      int s0 = __shfl(myidx, j + 0, 32);
      int s1 = __shfl(myidx, j + 1, 32);
      int s2 = __shfl(myidx, j + 2, 32);
      int s3 = __shfl(myidx, j + 3, 32);
      ushort4 v0 = *(const ushort4*)(xb + (size_t)s0 * F_IN + col);
      ushort4 v1 = *(const ushort4*)(xb + (size_t)s1 * F_IN + col);
      ushort4 v2 = *(const ushort4*)(xb + (size_t)s2 * F_IN + col);
      ushort4 v3 = *(const ushort4*)(xb + (size_t)s3 * F_IN + col);
      a0 += bf2f(v0.x) + bf2f(v1.x) + bf2f(v2.x) + bf2f(v3.x);
      a1 += bf2f(v0.y) + bf2f(v1.y) + bf2f(v2.y) + bf2f(v3.y);
      a2 += bf2f(v0.z) + bf2f(v1.z) + bf2f(v2.z) + bf2f(v3.z);
      a3 += bf2f(v0.w) + bf2f(v1.w) + bf2f(v2.w) + bf2f(v3.w);
    }
    for (; j < cnt; ++j) {
      int s = __shfl(myidx, j, 32);
      ushort4 v = *(const ushort4*)(xb + (size_t)s * F_IN + col);
      a0 += bf2f(v.x);
      a1 += bf2f(v.y);
      a2 += bf2f(v.z);
      a3 += bf2f(v.w);
    }
  }
  ushort4 o;
  o.x = f2bf(a0); o.y = f2bf(a1); o.z = f2bf(a2); o.w = f2bf(a3);
  *(ushort4*)(h_pre + (size_t)node * F_IN + col) = o;
}

// ---------------- GEMM1 (MFMA): h1 = relu(h_pre @ W1 + b1), bf16 --------
__global__ __launch_bounds__(256) void gemm1_mfma(
    const unsigned short* __restrict__ hpre,  // bf16 [N_NODES][128]
    const unsigned short* __restrict__ w1t,   // bf16 [256][128]
    const float* __restrict__ b1, __hip_bfloat16* __restrict__ h1) {
  __shared__ unsigned char Asm[64 * 128 * 2];  // 16 KB, swizzled
  int t = threadIdx.x;
  int lane = t & 63;
  int w = t >> 6;  // wave -> col quadrant
  int m0 = blockIdx.x * 64;

  for (int ci = t; ci < 1024; ci += 256) {
    int r = ci >> 4;
    int c8 = ci & 15;
    int gr = m0 + r;
    uint4 v = make_uint4(0, 0, 0, 0);
    if (gr < N_NODES) v = *(const uint4*)(hpre + (size_t)gr * F_IN + c8 * 8);
    int byte = (r * 256 + c8 * 16) ^ ((r & 7) << 4);
    *(uint4*)(Asm + byte) = v;
  }

  int fl = lane & 15;
  int fk = (lane >> 4) * 8;
  bf16x8 bfrag[4][4];
#pragma unroll
  for (int nt = 0; nt < 4; ++nt)
#pragma unroll
    for (int ks = 0; ks < 4; ++ks)
      bfrag[nt][ks] = *(const bf16x8*)(
          w1t + (size_t)(w * 64 + nt * 16 + fl) * F_IN + ks * 32 + fk);

  __syncthreads();

  f32x4 acc[4][4];
#pragma unroll
  for (int mt = 0; mt < 4; ++mt)
#pragma unroll
    for (int nt = 0; nt < 4; ++nt) acc[mt][nt] = f32x4{0.f, 0.f, 0.f, 0.f};

#pragma unroll
  for (int mt = 0; mt < 4; ++mt) {
    bf16x8 afrag[4];
#pragma unroll
    for (int ks = 0; ks < 4; ++ks) {
      int r = mt * 16 + fl;
      int byte = (r * 256 + (ks * 32 + fk) * 2) ^ ((r & 7) << 4);
      afrag[ks] = *(const bf16x8*)(Asm + byte);
    }
#pragma unroll
    for (int nt = 0; nt < 4; ++nt)
#pragma unroll
      for (int ks = 0; ks < 4; ++ks)
        acc[mt][nt] = __builtin_amdgcn_mfma_f32_16x16x32_bf16(
            afrag[ks], bfrag[nt][ks], acc[mt][nt], 0, 0, 0);
  }

  int rb = (lane >> 4) * 4;
#pragma unroll
  for (int mt = 0; mt < 4; ++mt) {
#pragma unroll
    for (int nt = 0; nt < 4; ++nt) {
      int gcol = w * 64 + nt * 16 + fl;
      float bias = b1[gcol];
#pragma unroll
      for (int j = 0; j < 4; ++j) {
        int grow = m0 + mt * 16 + rb + j;
        if (grow < N_NODES) {
          float v = fmaxf(acc[mt][nt][j] + bias, 0.f);
          h1[(size_t)grow * F_HID + gcol] = __float2bfloat16(v);
        }
      }
    }
  }
}

// ---------------- GEMM2: z0 = h1 @ W2  (no bias), thread-per-row --------
__global__ __launch_bounds__(256) void gemm2(
    const __hip_bfloat16* __restrict__ h1, const float* __restrict__ W2,
    float* __restrict__ z0) {
  __shared__ float w2s[F_HID * F_OUT];  // 24 KB
  int t = threadIdx.x;
  for (int i = t; i < F_HID * F_OUT; i += 256) w2s[i] = W2[i];
  __syncthreads();
  int row = blockIdx.x * 256 + t;
  if (row >= N_NODES) return;
  const uint4* hp = reinterpret_cast<const uint4*>(h1 + (size_t)row * F_HID);
  float acc[F_OUT];
#pragma unroll
  for (int j = 0; j < F_OUT; ++j) acc[j] = 0.f;

  for (int kc = 0; kc < F_HID / 8; ++kc) {
    uint4 u = hp[kc];  // 8 bf16
    float a[8];
    a[0] = __uint_as_float(u.x << 16);
    a[1] = __uint_as_float(u.x & 0xffff0000u);
    a[2] = __uint_as_float(u.y << 16);
    a[3] = __uint_as_float(u.y & 0xffff0000u);
    a[4] = __uint_as_float(u.z << 16);
    a[5] = __uint_as_float(u.z & 0xffff0000u);
    a[6] = __uint_as_float(u.w << 16);
    a[7] = __uint_as_float(u.w & 0xffff0000u);
#pragma unroll
    for (int j = 0; j < 8; ++j) {
      int k = kc * 8 + j;
      const float4* w4 = (const float4*)&w2s[k * F_OUT];
      float4 b0 = w4[0], b1v = w4[1], b2v = w4[2];
      float4 b3 = w4[3], b4 = w4[4], b5 = w4[5];
      float av = a[j];
      acc[0] += av * b0.x;  acc[1] += av * b0.y;
      acc[2] += av * b0.z;  acc[3] += av * b0.w;
      acc[4] += av * b1v.x; acc[5] += av * b1v.y;
      acc[6] += av * b1v.z; acc[7] += av * b1v.w;
      acc[8] += av * b2v.x; acc[9] += av * b2v.y;
      acc[10] += av * b2v.z; acc[11] += av * b2v.w;
      acc[12] += av * b3.x; acc[13] += av * b3.y;
      acc[14] += av * b3.z; acc[15] += av * b3.w;
      acc[16] += av * b4.x; acc[17] += av * b4.y;
      acc[18] += av * b4.z; acc[19] += av * b4.w;
      acc[20] += av * b5.x; acc[21] += av * b5.y;
      acc[22] += av * b5.z; acc[23] += av * b5.w;
    }
  }
  float* zp = z0 + (size_t)row * F_OUT;
#pragma unroll
  for (int j = 0; j < F_OUT; ++j) zp[j] = acc[j];
}

// ---------------- layer-2 aggregate + log_softmax (index-pipelined) -----
__global__ __launch_bounds__(256) void agg2_finalize(
    const float* __restrict__ z0, const int* __restrict__ row_start,
    const int* __restrict__ deg, const int* __restrict__ eidx,
    const float* __restrict__ b2, float* __restrict__ out) {
  int g = threadIdx.x >> 5;
  int c = threadIdx.x & 31;
  int node = blockIdx.x * 8 + g;
  if (node >= N_NODES) return;
  bool act = (c < F_OUT);
  float v = act ? (z0[(size_t)node * F_OUT + c] + b2[c]) : 0.f;

  int rs = row_start[node];
  int dg = deg[node];
  for (int base = 0; base < dg; base += 32) {
    int cnt = min(32, dg - base);
    int myidx = (c < cnt) ? eidx[rs + base + c] : 0;
    int j = 0;
    for (; j + 4 <= cnt; j += 4) {
      int s0 = __shfl(myidx, j + 0, 32);
      int s1 = __shfl(myidx, j + 1, 32);
      int s2 = __shfl(myidx, j + 2, 32);
      int s3 = __shfl(myidx, j + 3, 32);
      float v0 = act ? z0[(size_t)s0 * F_OUT + c] : 0.f;
      float v1 = act ? z0[(size_t)s1 * F_OUT + c] : 0.f;
      float v2 = act ? z0[(size_t)s2 * F_OUT + c] : 0.f;
      float v3 = act ? z0[(size_t)s3 * F_OUT + c] : 0.f;
      v += (v0 + v1) + (v2 + v3);
    }
    for (; j < cnt; ++j) {
      int s = __shfl(myidx, j, 32);
      v += act ? z0[(size_t)s * F_OUT + c] : 0.f;
    }
  }

  float mx = act ? v : -1e30f;
#pragma unroll
  for (int m = 16; m >= 1; m >>= 1) mx = fmaxf(mx, __shfl_xor(mx, m, 32));
  float e = act ? __expf(v - mx) : 0.f;
#pragma unroll
  for (int m = 16; m >= 1; m >>= 1) e += __shfl_xor(e, m, 32);
  float lse = mx + __logf(e);
  if (act) out[(size_t)node * F_OUT + c] = v - lse;
}

extern "C" void kernel_launch(void* const* d_in, const int* in_sizes, int n_in,
                              void* d_out, int out_size, void* d_ws,
                              size_t ws_size, hipStream_t stream) {
  const float* x = (const float*)d_in[0];
  const int* ei = (const int*)d_in[1];
  const float* W1 = (const float*)d_in[2];
  const float* b1 = (const float*)d_in[3];
  const float* W2 = (const float*)d_in[4];
  const float* b2 = (const float*)d_in[5];
  const int* src = ei;
  const int* dst = ei + N_EDGES;

  // workspace layout (bytes):
  //   deg       : [0,          400,000)
  //   cursor    : [400,000,    800,000)
  //   row_start : [800,000,  1,200,000)
  //   eidx      : [1,200,000, 3,600,000)
  //   xb        : [3,600,000, 29,200,000)   bf16 100000x128
  //   h_pre     : [29,200,000, 54,800,000)  bf16 100000x128
  //   h1        : [54,800,000,106,000,000)  bf16 100000x256
  //   z0        : [106,000,000,115,600,000) f32 100000x24
  //   blocksum  : [115,600,000,115,600,392) int 98
  //   w1t       : [115,600,400,115,665,936) bf16 256x128
  char* ws = (char*)d_ws;
  int* deg = (int*)ws;
  int* cursor = (int*)(ws + 400000);
  int* row_start = (int*)(ws + 800000);
  int* eidx = (int*)(ws + 1200000);
  unsigned short* xb = (unsigned short*)(ws + 3600000);
  unsigned short* h_pre = (unsigned short*)(ws + 29200000);
  __hip_bfloat16* h1 = (__hip_bfloat16*)(ws + 54800000);
  float* z0 = (float*)(ws + 106000000);
  int* blocksum = (int*)(ws + 115600000);
  unsigned short* w1t = (unsigned short*)(ws + 115600400);
  float* out = (float*)d_out;

  // zero deg + cursor (contiguous 800 KB)
  hipMemsetAsync(ws, 0, 800000, stream);

  const int EB = (N_EDGES + 255) / 256;
  hist_deg<<<EB, 256, 0, stream>>>(dst, deg);

  scan_partial<<<SCAN_NB, 256, 0, stream>>>(deg, blocksum);
  scan_blocksums<<<1, 128, 0, stream>>>(blocksum);
  scan_final<<<SCAN_NB, 256, 0, stream>>>(deg, blocksum, row_start);

  fill_csr<<<EB, 256, 0, stream>>>(src, dst, row_start, cursor, eidx);

  prep_xbf<<<2048, 256, 0, stream>>>(x, (unsigned int*)xb);
  prep_w1t<<<(F_IN * F_HID + 255) / 256, 256, 0, stream>>>(W1, w1t);

  agg1_gather<<<(N_NODES + 7) / 8, 256, 0, stream>>>(xb, row_start, deg,
                                                     eidx, h_pre);

  gemm1_mfma<<<(N_NODES + 63) / 64, 256, 0, stream>>>(h_pre, w1t, b1, h1);

  gemm2<<<(N_NODES + 255) / 256, 256, 0, stream>>>(h1, W2, z0);

  agg2_finalize<<<(N_NODES + 7) / 8, 256, 0, stream>>>(z0, row_start, deg,
                                                       eidx, b2, out);
}

// Round 8
// 267.015 us; speedup vs baseline: 4.8865x; 1.0991x over previous
//
#include <hip/hip_runtime.h>
#include <hip/hip_bf16.h>
#include <math.h>

#define N_NODES 100000
#define N_EDGES 600000
#define F_IN 128
#define F_HID 256
#define F_OUT 24
#define SCAN_NB 98  // ceil(100000/1024)

typedef __attribute__((ext_vector_type(8))) short bf16x8;
typedef __attribute__((ext_vector_type(4))) float f32x4;

__device__ inline unsigned short f2bf(float f) {
  __hip_bfloat16 h = __float2bfloat16(f);
  return *reinterpret_cast<unsigned short*>(&h);
}
__device__ inline float bf2f(unsigned short u) {
  return __uint_as_float(((unsigned int)u) << 16);
}

// ---------------- CSR build: degree histogram + per-edge rank ------------
// rank[e] = position of edge e within its dst bucket (atomic return value).
__global__ __launch_bounds__(256) void hist_rank(const int* __restrict__ dst,
                                                 int* __restrict__ deg,
                                                 int* __restrict__ rank) {
  int e = blockIdx.x * 256 + threadIdx.x;
  if (e >= N_EDGES) return;
  rank[e] = atomicAdd(&deg[dst[e]], 1);
}

// ---------------- multi-block exclusive scan, pass 1: block sums ---------
__global__ __launch_bounds__(256) void scan_partial(
    const int* __restrict__ deg, int* __restrict__ blocksum) {
  int t = threadIdx.x;
  int base = blockIdx.x * 1024 + t * 4;
  int s = 0;
  if (base + 3 < N_NODES) {
    int4 v = *(const int4*)(deg + base);
    s = v.x + v.y + v.z + v.w;
  } else {
    for (int i = base; i < N_NODES; ++i) s += deg[i];
  }
  __shared__ int red[4];
#pragma unroll
  for (int off = 32; off >= 1; off >>= 1) s += __shfl_down(s, off, 64);
  if ((t & 63) == 0) red[t >> 6] = s;
  __syncthreads();
  if (t == 0) blocksum[blockIdx.x] = red[0] + red[1] + red[2] + red[3];
}

// ---------------- scan pass 2: exclusive scan of 98 block sums ----------
__global__ __launch_bounds__(128) void scan_blocksums(int* __restrict__ bs) {
  __shared__ int sh[128];
  int t = threadIdx.x;
  int v = (t < SCAN_NB) ? bs[t] : 0;
  sh[t] = v;
  __syncthreads();
  for (int off = 1; off < 128; off <<= 1) {
    int u = (t >= off) ? sh[t - off] : 0;
    __syncthreads();
    sh[t] += u;
    __syncthreads();
  }
  if (t < SCAN_NB) bs[t] = sh[t] - v;  // exclusive
}

// ---------------- scan pass 3: per-block exclusive + offset -------------
__global__ __launch_bounds__(256) void scan_final(
    const int* __restrict__ deg, const int* __restrict__ blocksum,
    int* __restrict__ row_start) {
  __shared__ int sh[256];
  int t = threadIdx.x;
  int base = blockIdx.x * 1024 + t * 4;
  int d[4] = {0, 0, 0, 0};
  if (base + 3 < N_NODES) {
    int4 v = *(const int4*)(deg + base);
    d[0] = v.x; d[1] = v.y; d[2] = v.z; d[3] = v.w;
  } else {
#pragma unroll
    for (int i = 0; i < 4; ++i)
      if (base + i < N_NODES) d[i] = deg[base + i];
  }
  int ts = d[0] + d[1] + d[2] + d[3];
  sh[t] = ts;
  __syncthreads();
  for (int off = 1; off < 256; off <<= 1) {
    int u = (t >= off) ? sh[t - off] : 0;
    __syncthreads();
    sh[t] += u;
    __syncthreads();
  }
  int run = blocksum[blockIdx.x] + sh[t] - ts;
#pragma unroll
  for (int i = 0; i < 4; ++i) {
    if (base + i < N_NODES) row_start[base + i] = run;
    run += d[i];
  }
}

// ---------------- CSR fill: non-atomic (rank precomputed) ---------------
__global__ __launch_bounds__(256) void fill_csr(
    const int* __restrict__ src, const int* __restrict__ dst,
    const int* __restrict__ row_start, const int* __restrict__ rank,
    int* __restrict__ eidx) {
  int e = blockIdx.x * 256 + threadIdx.x;
  if (e >= N_EDGES) return;
  eidx[row_start[dst[e]] + rank[e]] = src[e];
}

// ---------------- prep: xb = bf16(x), 8 elems/thread streaming ----------
__global__ __launch_bounds__(256) void prep_xbf(
    const float* __restrict__ x, unsigned int* __restrict__ xb) {
  const int n8 = N_NODES * F_IN / 8;  // 1.6M
  int i = blockIdx.x * 256 + threadIdx.x;
  int stride = gridDim.x * 256;
  for (; i < n8; i += stride) {
    float4 a = ((const float4*)x)[i * 2];
    float4 b = ((const float4*)x)[i * 2 + 1];
    uint4 o;
    o.x = (unsigned)f2bf(a.x) | ((unsigned)f2bf(a.y) << 16);
    o.y = (unsigned)f2bf(a.z) | ((unsigned)f2bf(a.w) << 16);
    o.z = (unsigned)f2bf(b.x) | ((unsigned)f2bf(b.y) << 16);
    o.w = (unsigned)f2bf(b.z) | ((unsigned)f2bf(b.w) << 16);
    ((uint4*)xb)[i] = o;
  }
}

// ---------------- prep: w1t[n][k] = bf16(W1[k][n])  (256x128) -----------
__global__ __launch_bounds__(256) void prep_w1t(
    const float* __restrict__ W1, unsigned short* __restrict__ w1t) {
  int i = blockIdx.x * 256 + threadIdx.x;  // = n*128 + k
  if (i >= F_IN * F_HID) return;
  int n = i >> 7, k = i & 127;
  w1t[i] = f2bf(W1[k * F_HID + n]);
}

// ---------------- layer-1 aggregate (bf16 gather, index-pipelined) ------
__global__ __launch_bounds__(256) void agg1_gather(
    const unsigned short* __restrict__ xb, const int* __restrict__ row_start,
    const int* __restrict__ deg, const int* __restrict__ eidx,
    unsigned short* __restrict__ h_pre) {
  int g = threadIdx.x >> 5;
  int l = threadIdx.x & 31;
  int node = blockIdx.x * 8 + g;
  if (node >= N_NODES) return;
  int col = l * 4;

  ushort4 sv = *(const ushort4*)(xb + (size_t)node * F_IN + col);  // self
  float a0 = bf2f(sv.x), a1 = bf2f(sv.y), a2 = bf2f(sv.z), a3 = bf2f(sv.w);

  int rs = row_start[node];
  int dg = deg[node];
  for (int base = 0; base < dg; base += 32) {
    int cnt = min(32, dg - base);
    int myidx = (l < cnt) ? eidx[rs + base + l] : 0;
    int j = 0;
    for (; j + 4 <= cnt; j += 4) {
      int s0 = __shfl(myidx, j + 0, 32);
      int s1 = __shfl(myidx, j + 1, 32);
      int s2 = __shfl(myidx, j + 2, 32);
      int s3 = __shfl(myidx, j + 3, 32);
      ushort4 v0 = *(const ushort4*)(xb + (size_t)s0 * F_IN + col);
      ushort4 v1 = *(const ushort4*)(xb + (size_t)s1 * F_IN + col);
      ushort4 v2 = *(const ushort4*)(xb + (size_t)s2 * F_IN + col);
      ushort4 v3 = *(const ushort4*)(xb + (size_t)s3 * F_IN + col);
      a0 += bf2f(v0.x) + bf2f(v1.x) + bf2f(v2.x) + bf2f(v3.x);
      a1 += bf2f(v0.y) + bf2f(v1.y) + bf2f(v2.y) + bf2f(v3.y);
      a2 += bf2f(v0.z) + bf2f(v1.z) + bf2f(v2.z) + bf2f(v3.z);
      a3 += bf2f(v0.w) + bf2f(v1.w) + bf2f(v2.w) + bf2f(v3.w);
    }
    for (; j < cnt; ++j) {
      int s = __shfl(myidx, j, 32);
      ushort4 v = *(const ushort4*)(xb + (size_t)s * F_IN + col);
      a0 += bf2f(v.x);
      a1 += bf2f(v.y);
      a2 += bf2f(v.z);
      a3 += bf2f(v.w);
    }
  }
  ushort4 o;
  o.x = f2bf(a0); o.y = f2bf(a1); o.z = f2bf(a2); o.w = f2bf(a3);
  *(ushort4*)(h_pre + (size_t)node * F_IN + col) = o;
}

// ---------------- GEMM1 (MFMA): h1 = relu(h_pre @ W1 + b1), bf16 --------
// A staged in 16KB swizzled LDS; C staged in LDS (overlaid) for coalesced
// uint4 global stores.
__global__ __launch_bounds__(256) void gemm1_mfma(
    const unsigned short* __restrict__ hpre,  // bf16 [N_NODES][128]
    const unsigned short* __restrict__ w1t,   // bf16 [256][128]
    const float* __restrict__ b1, __hip_bfloat16* __restrict__ h1) {
  __shared__ unsigned char smem[64 * 264 * 2];  // 33 KB (A uses first 16 KB)
  int t = threadIdx.x;
  int lane = t & 63;
  int w = t >> 6;  // wave -> col quadrant
  int m0 = blockIdx.x * 64;

  // stage A tile 64x128 bf16, swizzled
  for (int ci = t; ci < 1024; ci += 256) {
    int r = ci >> 4;
    int c8 = ci & 15;
    int gr = m0 + r;
    uint4 v = make_uint4(0, 0, 0, 0);
    if (gr < N_NODES) v = *(const uint4*)(hpre + (size_t)gr * F_IN + c8 * 8);
    int byte = (r * 256 + c8 * 16) ^ ((r & 7) << 4);
    *(uint4*)(smem + byte) = v;
  }

  int fl = lane & 15;
  int fk = (lane >> 4) * 8;
  bf16x8 bfrag[4][4];
#pragma unroll
  for (int nt = 0; nt < 4; ++nt)
#pragma unroll
    for (int ks = 0; ks < 4; ++ks)
      bfrag[nt][ks] = *(const bf16x8*)(
          w1t + (size_t)(w * 64 + nt * 16 + fl) * F_IN + ks * 32 + fk);

  __syncthreads();

  f32x4 acc[4][4];
#pragma unroll
  for (int mt = 0; mt < 4; ++mt)
#pragma unroll
    for (int nt = 0; nt < 4; ++nt) acc[mt][nt] = f32x4{0.f, 0.f, 0.f, 0.f};

#pragma unroll
  for (int mt = 0; mt < 4; ++mt) {
    bf16x8 afrag[4];
#pragma unroll
    for (int ks = 0; ks < 4; ++ks) {
      int r = mt * 16 + fl;
      int byte = (r * 256 + (ks * 32 + fk) * 2) ^ ((r & 7) << 4);
      afrag[ks] = *(const bf16x8*)(smem + byte);
    }
#pragma unroll
    for (int nt = 0; nt < 4; ++nt)
#pragma unroll
      for (int ks = 0; ks < 4; ++ks)
        acc[mt][nt] = __builtin_amdgcn_mfma_f32_16x16x32_bf16(
            afrag[ks], bfrag[nt][ks], acc[mt][nt], 0, 0, 0);
  }

  // epilogue: stage C tile in LDS (overlay A region), then coalesced store
  __syncthreads();  // all A reads done before overwrite
  unsigned short* Csm = (unsigned short*)smem;
  const int CS = 264;  // row stride in ushorts (padded)
  int rb = (lane >> 4) * 4;
#pragma unroll
  for (int mt = 0; mt < 4; ++mt) {
#pragma unroll
    for (int nt = 0; nt < 4; ++nt) {
      int gcol = w * 64 + nt * 16 + fl;
      float bias = b1[gcol];
#pragma unroll
      for (int j = 0; j < 4; ++j) {
        float v = fmaxf(acc[mt][nt][j] + bias, 0.f);
        Csm[(mt * 16 + rb + j) * CS + gcol] = f2bf(v);
      }
    }
  }
  __syncthreads();
  // 64 rows x 512B, 16B chunks: 2048 chunks over 256 threads = 8 iters
  for (int ci = t; ci < 2048; ci += 256) {
    int r = ci >> 5, c16 = ci & 31;
    int grow = m0 + r;
    if (grow < N_NODES) {
      uint4 v = *(const uint4*)(Csm + r * CS + c16 * 8);
      *(uint4*)((unsigned short*)h1 + (size_t)grow * F_HID + c16 * 8) = v;
    }
  }
}

// ---------------- GEMM2: z0 = h1 @ W2  (no bias), thread-per-row --------
__global__ __launch_bounds__(256) void gemm2(
    const __hip_bfloat16* __restrict__ h1, const float* __restrict__ W2,
    float* __restrict__ z0) {
  __shared__ float w2s[F_HID * F_OUT];  // 24 KB
  int t = threadIdx.x;
  for (int i = t; i < F_HID * F_OUT; i += 256) w2s[i] = W2[i];
  __syncthreads();
  int row = blockIdx.x * 256 + t;
  if (row >= N_NODES) return;
  const uint4* hp = reinterpret_cast<const uint4*>(h1 + (size_t)row * F_HID);
  float acc[F_OUT];
#pragma unroll
  for (int j = 0; j < F_OUT; ++j) acc[j] = 0.f;

  for (int kc = 0; kc < F_HID / 8; ++kc) {
    uint4 u = hp[kc];  // 8 bf16
    float a[8];
    a[0] = __uint_as_float(u.x << 16);
    a[1] = __uint_as_float(u.x & 0xffff0000u);
    a[2] = __uint_as_float(u.y << 16);
    a[3] = __uint_as_float(u.y & 0xffff0000u);
    a[4] = __uint_as_float(u.z << 16);
    a[5] = __uint_as_float(u.z & 0xffff0000u);
    a[6] = __uint_as_float(u.w << 16);
    a[7] = __uint_as_float(u.w & 0xffff0000u);
#pragma unroll
    for (int j = 0; j < 8; ++j) {
      int k = kc * 8 + j;
      const float4* w4 = (const float4*)&w2s[k * F_OUT];
      float4 b0 = w4[0], b1v = w4[1], b2v = w4[2];
      float4 b3 = w4[3], b4 = w4[4], b5 = w4[5];
      float av = a[j];
      acc[0] += av * b0.x;  acc[1] += av * b0.y;
      acc[2] += av * b0.z;  acc[3] += av * b0.w;
      acc[4] += av * b1v.x; acc[5] += av * b1v.y;
      acc[6] += av * b1v.z; acc[7] += av * b1v.w;
      acc[8] += av * b2v.x; acc[9] += av * b2v.y;
      acc[10] += av * b2v.z; acc[11] += av * b2v.w;
      acc[12] += av * b3.x; acc[13] += av * b3.y;
      acc[14] += av * b3.z; acc[15] += av * b3.w;
      acc[16] += av * b4.x; acc[17] += av * b4.y;
      acc[18] += av * b4.z; acc[19] += av * b4.w;
      acc[20] += av * b5.x; acc[21] += av * b5.y;
      acc[22] += av * b5.z; acc[23] += av * b5.w;
    }
  }
  float* zp = z0 + (size_t)row * F_OUT;
#pragma unroll
  for (int j = 0; j < F_OUT; ++j) zp[j] = acc[j];
}

// ---------------- layer-2 aggregate + log_softmax (index-pipelined) -----
__global__ __launch_bounds__(256) void agg2_finalize(
    const float* __restrict__ z0, const int* __restrict__ row_start,
    const int* __restrict__ deg, const int* __restrict__ eidx,
    const float* __restrict__ b2, float* __restrict__ out) {
  int g = threadIdx.x >> 5;
  int c = threadIdx.x & 31;
  int node = blockIdx.x * 8 + g;
  if (node >= N_NODES) return;
  bool act = (c < F_OUT);
  float v = act ? (z0[(size_t)node * F_OUT + c] + b2[c]) : 0.f;

  int rs = row_start[node];
  int dg = deg[node];
  for (int base = 0; base < dg; base += 32) {
    int cnt = min(32, dg - base);
    int myidx = (c < cnt) ? eidx[rs + base + c] : 0;
    int j = 0;
    for (; j + 4 <= cnt; j += 4) {
      int s0 = __shfl(myidx, j + 0, 32);
      int s1 = __shfl(myidx, j + 1, 32);
      int s2 = __shfl(myidx, j + 2, 32);
      int s3 = __shfl(myidx, j + 3, 32);
      float v0 = act ? z0[(size_t)s0 * F_OUT + c] : 0.f;
      float v1 = act ? z0[(size_t)s1 * F_OUT + c] : 0.f;
      float v2 = act ? z0[(size_t)s2 * F_OUT + c] : 0.f;
      float v3 = act ? z0[(size_t)s3 * F_OUT + c] : 0.f;
      v += (v0 + v1) + (v2 + v3);
    }
    for (; j < cnt; ++j) {
      int s = __shfl(myidx, j, 32);
      v += act ? z0[(size_t)s * F_OUT + c] : 0.f;
    }
  }

  float mx = act ? v : -1e30f;
#pragma unroll
  for (int m = 16; m >= 1; m >>= 1) mx = fmaxf(mx, __shfl_xor(mx, m, 32));
  float e = act ? __expf(v - mx) : 0.f;
#pragma unroll
  for (int m = 16; m >= 1; m >>= 1) e += __shfl_xor(e, m, 32);
  float lse = mx + __logf(e);
  if (act) out[(size_t)node * F_OUT + c] = v - lse;
}

extern "C" void kernel_launch(void* const* d_in, const int* in_sizes, int n_in,
                              void* d_out, int out_size, void* d_ws,
                              size_t ws_size, hipStream_t stream) {
  const float* x = (const float*)d_in[0];
  const int* ei = (const int*)d_in[1];
  const float* W1 = (const float*)d_in[2];
  const float* b1 = (const float*)d_in[3];
  const float* W2 = (const float*)d_in[4];
  const float* b2 = (const float*)d_in[5];
  const int* src = ei;
  const int* dst = ei + N_EDGES;

  // workspace layout (bytes):
  //   deg       : [0,          400,000)
  //   row_start : [400,000,    800,000)
  //   rank      : [800,000,  3,200,000)
  //   eidx      : [3,200,000, 5,600,000)
  //   xb        : [5,600,000, 31,200,000)   bf16 100000x128
  //   h_pre     : [31,200,000, 56,800,000)  bf16 100000x128
  //   h1        : [56,800,000,108,000,000)  bf16 100000x256
  //   z0        : [108,000,000,117,600,000) f32 100000x24
  //   blocksum  : [117,600,000,117,600,392) int 98
  //   w1t       : [117,600,400,117,665,936) bf16 256x128
  char* ws = (char*)d_ws;
  int* deg = (int*)ws;
  int* row_start = (int*)(ws + 400000);
  int* rank = (int*)(ws + 800000);
  int* eidx = (int*)(ws + 3200000);
  unsigned short* xb = (unsigned short*)(ws + 5600000);
  unsigned short* h_pre = (unsigned short*)(ws + 31200000);
  __hip_bfloat16* h1 = (__hip_bfloat16*)(ws + 56800000);
  float* z0 = (float*)(ws + 108000000);
  int* blocksum = (int*)(ws + 117600000);
  unsigned short* w1t = (unsigned short*)(ws + 117600400);
  float* out = (float*)d_out;

  // zero deg only (cursor eliminated)
  hipMemsetAsync(ws, 0, 400000, stream);

  const int EB = (N_EDGES + 255) / 256;
  hist_rank<<<EB, 256, 0, stream>>>(dst, deg, rank);

  scan_partial<<<SCAN_NB, 256, 0, stream>>>(deg, blocksum);
  scan_blocksums<<<1, 128, 0, stream>>>(blocksum);
  scan_final<<<SCAN_NB, 256, 0, stream>>>(deg, blocksum, row_start);

  fill_csr<<<EB, 256, 0, stream>>>(src, dst, row_start, rank, eidx);

  prep_xbf<<<2048, 256, 0, stream>>>(x, (unsigned int*)xb);
  prep_w1t<<<(F_IN * F_HID + 255) / 256, 256, 0, stream>>>(W1, w1t);

  agg1_gather<<<(N_NODES + 7) / 8, 256, 0, stream>>>(xb, row_start, deg,
                                                     eidx, h_pre);

  gemm1_mfma<<<(N_NODES + 63) / 64, 256, 0, stream>>>(h_pre, w1t, b1, h1);

  gemm2<<<(N_NODES + 255) / 256, 256, 0, stream>>>(h1, W2, z0);

  agg2_finalize<<<(N_NODES + 7) / 8, 256, 0, stream>>>(z0, row_start, deg,
                                                       eidx, b2, out);
}

// Round 12
// 238.368 us; speedup vs baseline: 5.4738x; 1.1202x over previous
//
#include <hip/hip_runtime.h>
#include <hip/hip_bf16.h>
#include <math.h>

#define N_NODES 100000
#define N_EDGES 600000
#define F_IN 128
#define F_HID 256
#define F_OUT 24
#define SCAN_NB 98  // ceil(100000/1024)

typedef __attribute__((ext_vector_type(8))) short bf16x8;
typedef __attribute__((ext_vector_type(4))) float f32x4;

__device__ inline unsigned short f2bf(float f) {
  __hip_bfloat16 h = __float2bfloat16(f);
  return *reinterpret_cast<unsigned short*>(&h);
}
__device__ inline float bf2f(unsigned short u) {
  return __uint_as_float(((unsigned int)u) << 16);
}

// ---------------- CSR build: degree histogram + per-edge rank ------------
__global__ __launch_bounds__(256) void hist_rank(const int* __restrict__ dst,
                                                 int* __restrict__ deg,
                                                 int* __restrict__ rank) {
  int e = blockIdx.x * 256 + threadIdx.x;
  if (e >= N_EDGES) return;
  rank[e] = atomicAdd(&deg[dst[e]], 1);
}

// ---------------- multi-block exclusive scan, pass 1: block sums ---------
__global__ __launch_bounds__(256) void scan_partial(
    const int* __restrict__ deg, int* __restrict__ blocksum) {
  int t = threadIdx.x;
  int base = blockIdx.x * 1024 + t * 4;
  int s = 0;
  if (base + 3 < N_NODES) {
    int4 v = *(const int4*)(deg + base);
    s = v.x + v.y + v.z + v.w;
  } else {
    for (int i = base; i < N_NODES; ++i) s += deg[i];
  }
  __shared__ int red[4];
#pragma unroll
  for (int off = 32; off >= 1; off >>= 1) s += __shfl_down(s, off, 64);
  if ((t & 63) == 0) red[t >> 6] = s;
  __syncthreads();
  if (t == 0) blocksum[blockIdx.x] = red[0] + red[1] + red[2] + red[3];
}

// ---------------- scan pass 2: exclusive scan of 98 block sums ----------
__global__ __launch_bounds__(128) void scan_blocksums(int* __restrict__ bs) {
  __shared__ int sh[128];
  int t = threadIdx.x;
  int v = (t < SCAN_NB) ? bs[t] : 0;
  sh[t] = v;
  __syncthreads();
  for (int off = 1; off < 128; off <<= 1) {
    int u = (t >= off) ? sh[t - off] : 0;
    __syncthreads();
    sh[t] += u;
    __syncthreads();
  }
  if (t < SCAN_NB) bs[t] = sh[t] - v;  // exclusive
}

// ---------------- scan pass 3: per-block exclusive + offset -------------
__global__ __launch_bounds__(256) void scan_final(
    const int* __restrict__ deg, const int* __restrict__ blocksum,
    int* __restrict__ row_start) {
  __shared__ int sh[256];
  int t = threadIdx.x;
  int base = blockIdx.x * 1024 + t * 4;
  int d[4] = {0, 0, 0, 0};
  if (base + 3 < N_NODES) {
    int4 v = *(const int4*)(deg + base);
    d[0] = v.x; d[1] = v.y; d[2] = v.z; d[3] = v.w;
  } else {
#pragma unroll
    for (int i = 0; i < 4; ++i)
      if (base + i < N_NODES) d[i] = deg[base + i];
  }
  int ts = d[0] + d[1] + d[2] + d[3];
  sh[t] = ts;
  __syncthreads();
  for (int off = 1; off < 256; off <<= 1) {
    int u = (t >= off) ? sh[t - off] : 0;
    __syncthreads();
    sh[t] += u;
    __syncthreads();
  }
  int run = blocksum[blockIdx.x] + sh[t] - ts;
#pragma unroll
  for (int i = 0; i < 4; ++i) {
    if (base + i < N_NODES) row_start[base + i] = run;
    run += d[i];
  }
}

// ---------------- CSR fill: non-atomic (rank precomputed) ---------------
__global__ __launch_bounds__(256) void fill_csr(
    const int* __restrict__ src, const int* __restrict__ dst,
    const int* __restrict__ row_start, const int* __restrict__ rank,
    int* __restrict__ eidx) {
  int e = blockIdx.x * 256 + threadIdx.x;
  if (e >= N_EDGES) return;
  eidx[row_start[dst[e]] + rank[e]] = src[e];
}

// ---------------- prep (fused): xb = bf16(x); w1t; w2b ------------------
// w1t[n][k] = bf16(W1[k][n])          (256x128)
// w2b[c][k] = bf16(W2[k][c]), c<24; 0 for c in [24,32)   (32x256)
__global__ __launch_bounds__(256) void prep_all(
    const float* __restrict__ x, const float* __restrict__ W1,
    const float* __restrict__ W2, unsigned int* __restrict__ xb,
    unsigned short* __restrict__ w1t, unsigned short* __restrict__ w2b) {
  const int n8 = N_NODES * F_IN / 8;  // 1.6M
  int tid = blockIdx.x * 256 + threadIdx.x;
  int stride = gridDim.x * 256;
  for (int i = tid; i < n8; i += stride) {
    float4 a = ((const float4*)x)[i * 2];
    float4 b = ((const float4*)x)[i * 2 + 1];
    uint4 o;
    o.x = (unsigned)f2bf(a.x) | ((unsigned)f2bf(a.y) << 16);
    o.y = (unsigned)f2bf(a.z) | ((unsigned)f2bf(a.w) << 16);
    o.z = (unsigned)f2bf(b.x) | ((unsigned)f2bf(b.y) << 16);
    o.w = (unsigned)f2bf(b.z) | ((unsigned)f2bf(b.w) << 16);
    ((uint4*)xb)[i] = o;
  }
  for (int i = tid; i < F_IN * F_HID; i += stride) {  // 32768
    int n = i >> 7, k = i & 127;
    w1t[i] = f2bf(W1[k * F_HID + n]);
  }
  for (int i = tid; i < 32 * F_HID; i += stride) {  // 8192
    int c = i >> 8, k = i & 255;
    w2b[i] = (c < F_OUT) ? f2bf(W2[k * F_OUT + c]) : 0;
  }
}

// ---------------- layer-1 aggregate (bf16 gather, index-pipelined) ------
__global__ __launch_bounds__(256) void agg1_gather(
    const unsigned short* __restrict__ xb, const int* __restrict__ row_start,
    const int* __restrict__ deg, const int* __restrict__ eidx,
    unsigned short* __restrict__ h_pre) {
  int g = threadIdx.x >> 5;
  int l = threadIdx.x & 31;
  int node = blockIdx.x * 8 + g;
  if (node >= N_NODES) return;
  int col = l * 4;

  ushort4 sv = *(const ushort4*)(xb + (size_t)node * F_IN + col);  // self
  float a0 = bf2f(sv.x), a1 = bf2f(sv.y), a2 = bf2f(sv.z), a3 = bf2f(sv.w);

  int rs = row_start[node];
  int dg = deg[node];
  for (int base = 0; base < dg; base += 32) {
    int cnt = min(32, dg - base);
    int myidx = (l < cnt) ? eidx[rs + base + l] : 0;
    int j = 0;
    for (; j + 4 <= cnt; j += 4) {
      int s0 = __shfl(myidx, j + 0, 32);
      int s1 = __shfl(myidx, j + 1, 32);
      int s2 = __shfl(myidx, j + 2, 32);
      int s3 = __shfl(myidx, j + 3, 32);
      ushort4 v0 = *(const ushort4*)(xb + (size_t)s0 * F_IN + col);
      ushort4 v1 = *(const ushort4*)(xb + (size_t)s1 * F_IN + col);
      ushort4 v2 = *(const ushort4*)(xb + (size_t)s2 * F_IN + col);
      ushort4 v3 = *(const ushort4*)(xb + (size_t)s3 * F_IN + col);
      a0 += bf2f(v0.x) + bf2f(v1.x) + bf2f(v2.x) + bf2f(v3.x);
      a1 += bf2f(v0.y) + bf2f(v1.y) + bf2f(v2.y) + bf2f(v3.y);
      a2 += bf2f(v0.z) + bf2f(v1.z) + bf2f(v2.z) + bf2f(v3.z);
      a3 += bf2f(v0.w) + bf2f(v1.w) + bf2f(v2.w) + bf2f(v3.w);
    }
    for (; j < cnt; ++j) {
      int s = __shfl(myidx, j, 32);
      ushort4 v = *(const ushort4*)(xb + (size_t)s * F_IN + col);
      a0 += bf2f(v.x);
      a1 += bf2f(v.y);
      a2 += bf2f(v.z);
      a3 += bf2f(v.w);
    }
  }
  ushort4 o;
  o.x = f2bf(a0); o.y = f2bf(a1); o.z = f2bf(a2); o.w = f2bf(a3);
  *(ushort4*)(h_pre + (size_t)node * F_IN + col) = o;
}

// ---------------- fused GEMM1+GEMM2 (MFMA x2): z0 = relu(h_pre@W1+b1)@W2
// Phase 1: A(h_pre 64x128) @ W1 -> h1 tile (64x256 bf16) staged in LDS.
// Phase 2: h1 tile (LDS) @ w2b -> z0 (64x24 f32) stored direct.
// h1 never touches HBM.
__global__ __launch_bounds__(256) void gemm12_fused(
    const unsigned short* __restrict__ hpre,  // bf16 [N_NODES][128]
    const unsigned short* __restrict__ w1t,   // bf16 [256][128]
    const unsigned short* __restrict__ w2b,   // bf16 [32][256] (padded)
    const float* __restrict__ b1, float* __restrict__ z0) {
  __shared__ unsigned char smem[64 * 264 * 2];  // 33 KB; A tile in first 16 KB
  int t = threadIdx.x;
  int lane = t & 63;
  int w = t >> 6;  // wave id
  int m0 = blockIdx.x * 64;

  // stage A tile 64x128 bf16, XOR-swizzled
  for (int ci = t; ci < 1024; ci += 256) {
    int r = ci >> 4;
    int c8 = ci & 15;
    int gr = m0 + r;
    uint4 v = make_uint4(0, 0, 0, 0);
    if (gr < N_NODES) v = *(const uint4*)(hpre + (size_t)gr * F_IN + c8 * 8);
    int byte = (r * 256 + c8 * 16) ^ ((r & 7) << 4);
    *(uint4*)(smem + byte) = v;
  }

  int fl = lane & 15;
  int fk = (lane >> 4) * 8;
  bf16x8 bfrag[4][4];  // W1 fragments: wave's 64-col quadrant
#pragma unroll
  for (int nt = 0; nt < 4; ++nt)
#pragma unroll
    for (int ks = 0; ks < 4; ++ks)
      bfrag[nt][ks] = *(const bf16x8*)(
          w1t + (size_t)(w * 64 + nt * 16 + fl) * F_IN + ks * 32 + fk);

  __syncthreads();

  f32x4 acc[4][4];
#pragma unroll
  for (int mt = 0; mt < 4; ++mt)
#pragma unroll
    for (int nt = 0; nt < 4; ++nt) acc[mt][nt] = f32x4{0.f, 0.f, 0.f, 0.f};

#pragma unroll
  for (int mt = 0; mt < 4; ++mt) {
    bf16x8 afrag[4];
#pragma unroll
    for (int ks = 0; ks < 4; ++ks) {
      int r = mt * 16 + fl;
      int byte = (r * 256 + (ks * 32 + fk) * 2) ^ ((r & 7) << 4);
      afrag[ks] = *(const bf16x8*)(smem + byte);
    }
#pragma unroll
    for (int nt = 0; nt < 4; ++nt)
#pragma unroll
      for (int ks = 0; ks < 4; ++ks)
        acc[mt][nt] = __builtin_amdgcn_mfma_f32_16x16x32_bf16(
            afrag[ks], bfrag[nt][ks], acc[mt][nt], 0, 0, 0);
  }

  // stage h1 tile (bias+relu, bf16) into LDS (overlays A region)
  __syncthreads();  // all A reads done before overwrite
  unsigned short* Csm = (unsigned short*)smem;
  const int CS = 264;  // row stride in ushorts (padded)
  int rb = (lane >> 4) * 4;
#pragma unroll
  for (int mt = 0; mt < 4; ++mt) {
#pragma unroll
    for (int nt = 0; nt < 4; ++nt) {
      int gcol = w * 64 + nt * 16 + fl;
      float bias = b1[gcol];
#pragma unroll
      for (int j = 0; j < 4; ++j) {
        float v = fmaxf(acc[mt][nt][j] + bias, 0.f);
        Csm[(mt * 16 + rb + j) * CS + gcol] = f2bf(v);
      }
    }
  }
  __syncthreads();

  // phase 2: z = h1tile @ W2. Wave w owns rows w*16..w*16+15.
  // B fragments from w2b (L2-hot, 16 KB): 2 col-tiles (cols 0-15, 16-31).
  bf16x8 b2frag[2][8];
#pragma unroll
  for (int ct = 0; ct < 2; ++ct)
#pragma unroll
    for (int ks = 0; ks < 8; ++ks)
      b2frag[ct][ks] = *(const bf16x8*)(
          w2b + (size_t)(ct * 16 + fl) * F_HID + ks * 32 + fk);

  f32x4 zacc[2] = {f32x4{0.f, 0.f, 0.f, 0.f}, f32x4{0.f, 0.f, 0.f, 0.f}};
#pragma unroll
  for (int ks = 0; ks < 8; ++ks) {
    bf16x8 a2 = *(const bf16x8*)(Csm + (w * 16 + fl) * CS + ks * 32 + fk);
#pragma unroll
    for (int ct = 0; ct < 2; ++ct)
      zacc[ct] = __builtin_amdgcn_mfma_f32_16x16x32_bf16(a2, b2frag[ct][ks],
                                                         zacc[ct], 0, 0, 0);
  }

#pragma unroll
  for (int ct = 0; ct < 2; ++ct) {
    int gcol = ct * 16 + fl;
    if (gcol < F_OUT) {
#pragma unroll
      for (int j = 0; j < 4; ++j) {
        int grow = m0 + w * 16 + rb + j;
        if (grow < N_NODES) z0[(size_t)grow * F_OUT + gcol] = zacc[ct][j];
      }
    }
  }
}

// ---------------- layer-2 aggregate + log_softmax (index-pipelined) -----
__global__ __launch_bounds__(256) void agg2_finalize(
    const float* __restrict__ z0, const int* __restrict__ row_start,
    const int* __restrict__ deg, const int* __restrict__ eidx,
    const float* __restrict__ b2, float* __restrict__ out) {
  int g = threadIdx.x >> 5;
  int c = threadIdx.x & 31;
  int node = blockIdx.x * 8 + g;
  if (node >= N_NODES) return;
  bool act = (c < F_OUT);
  float v = act ? (z0[(size_t)node * F_OUT + c] + b2[c]) : 0.f;

  int rs = row_start[node];
  int dg = deg[node];
  for (int base = 0; base < dg; base += 32) {
    int cnt = min(32, dg - base);
    int myidx = (c < cnt) ? eidx[rs + base + c] : 0;
    int j = 0;
    for (; j + 4 <= cnt; j += 4) {
      int s0 = __shfl(myidx, j + 0, 32);
      int s1 = __shfl(myidx, j + 1, 32);
      int s2 = __shfl(myidx, j + 2, 32);
      int s3 = __shfl(myidx, j + 3, 32);
      float v0 = act ? z0[(size_t)s0 * F_OUT + c] : 0.f;
      float v1 = act ? z0[(size_t)s1 * F_OUT + c] : 0.f;
      float v2 = act ? z0[(size_t)s2 * F_OUT + c] : 0.f;
      float v3 = act ? z0[(size_t)s3 * F_OUT + c] : 0.f;
      v += (v0 + v1) + (v2 + v3);
    }
    for (; j < cnt; ++j) {
      int s = __shfl(myidx, j, 32);
      v += act ? z0[(size_t)s * F_OUT + c] : 0.f;
    }
  }

  float mx = act ? v : -1e30f;
#pragma unroll
  for (int m = 16; m >= 1; m >>= 1) mx = fmaxf(mx, __shfl_xor(mx, m, 32));
  float e = act ? __expf(v - mx) : 0.f;
#pragma unroll
  for (int m = 16; m >= 1; m >>= 1) e += __shfl_xor(e, m, 32);
  float lse = mx + __logf(e);
  if (act) out[(size_t)node * F_OUT + c] = v - lse;
}

extern "C" void kernel_launch(void* const* d_in, const int* in_sizes, int n_in,
                              void* d_out, int out_size, void* d_ws,
                              size_t ws_size, hipStream_t stream) {
  const float* x = (const float*)d_in[0];
  const int* ei = (const int*)d_in[1];
  const float* W1 = (const float*)d_in[2];
  const float* b1 = (const float*)d_in[3];
  const float* W2 = (const float*)d_in[4];
  const float* b2 = (const float*)d_in[5];
  const int* src = ei;
  const int* dst = ei + N_EDGES;

  // workspace layout (bytes):
  //   deg       : [0,          400,000)
  //   row_start : [400,000,    800,000)
  //   rank      : [800,000,  3,200,000)
  //   eidx      : [3,200,000, 5,600,000)
  //   xb        : [5,600,000, 31,200,000)   bf16 100000x128
  //   h_pre     : [31,200,000, 56,800,000)  bf16 100000x128
  //   z0        : [56,800,000, 66,400,000)  f32 100000x24
  //   blocksum  : [66,400,000, 66,400,392)  int 98
  //   w1t       : [66,400,400, 66,465,936)  bf16 256x128
  //   w2b       : [66,465,936, 66,482,320)  bf16 32x256
  char* ws = (char*)d_ws;
  int* deg = (int*)ws;
  int* row_start = (int*)(ws + 400000);
  int* rank = (int*)(ws + 800000);
  int* eidx = (int*)(ws + 3200000);
  unsigned short* xb = (unsigned short*)(ws + 5600000);
  unsigned short* h_pre = (unsigned short*)(ws + 31200000);
  float* z0 = (float*)(ws + 56800000);
  int* blocksum = (int*)(ws + 66400000);
  unsigned short* w1t = (unsigned short*)(ws + 66400400);
  unsigned short* w2b = (unsigned short*)(ws + 66465936);
  float* out = (float*)d_out;

  // zero deg
  hipMemsetAsync(ws, 0, 400000, stream);

  const int EB = (N_EDGES + 255) / 256;
  hist_rank<<<EB, 256, 0, stream>>>(dst, deg, rank);

  scan_partial<<<SCAN_NB, 256, 0, stream>>>(deg, blocksum);
  scan_blocksums<<<1, 128, 0, stream>>>(blocksum);
  scan_final<<<SCAN_NB, 256, 0, stream>>>(deg, blocksum, row_start);

  fill_csr<<<EB, 256, 0, stream>>>(src, dst, row_start, rank, eidx);

  prep_all<<<2048, 256, 0, stream>>>(x, W1, W2, (unsigned int*)xb, w1t, w2b);

  agg1_gather<<<(N_NODES + 7) / 8, 256, 0, stream>>>(xb, row_start, deg,
                                                     eidx, h_pre);

  gemm12_fused<<<(N_NODES + 63) / 64, 256, 0, stream>>>(h_pre, w1t, w2b, b1,
                                                        z0);

  agg2_finalize<<<(N_NODES + 7) / 8, 256, 0, stream>>>(z0, row_start, deg,
                                                       eidx, b2, out);
}